// Round 1
// baseline (9346.614 us; speedup 1.0000x reference)
//
#include <hip/hip_runtime.h>
#include <cstdint>
#include <cstddef>
#include <math.h>

// Problem dims (fixed)
#define LL  8
#define BB  2
#define SS  1024
#define DD  1024
#define HH  16
#define HD  64
#define FFD 4096
#define BSD (BB*SS*DD)   // 2,097,152

// ---------------------------------------------------------------------------
// GEMM: C[M,N] = A[M,K] * W[N,K]^T + bias[N]
// mode 0: plain   mode 1: relu   mode 2: QKV split (cols [0,D)->C, [D,2D)->Ck,
//                                         [2D,3D)->Cv, each with ldc=D)
// Tile 64x64, BK=16, 256 threads, 4x4 accum per thread. f32.
// ---------------------------------------------------------------------------
__global__ __launch_bounds__(256)
void gemm_kernel(const float* __restrict__ A, const float* __restrict__ W,
                 const float* __restrict__ bias, float* __restrict__ C,
                 float* __restrict__ Ck, float* __restrict__ Cv,
                 int M, int N, int K, int mode)
{
    __shared__ float As[16][68];   // [k][m], row stride 68 floats (16B-aligned rows)
    __shared__ float Ws[16][68];   // [k][n]

    const int tid = threadIdx.x;
    const int tx  = tid & 15;      // 0..15 -> n
    const int ty  = tid >> 4;      // 0..15 -> m
    const int m0  = blockIdx.y * 64;
    const int n0  = blockIdx.x * 64;

    float acc[4][4];
    #pragma unroll
    for (int i = 0; i < 4; ++i)
        #pragma unroll
        for (int j = 0; j < 4; ++j) acc[i][j] = 0.f;

    for (int kt = 0; kt < K; kt += 16) {
        #pragma unroll
        for (int i = 0; i < 4; ++i) {
            int e = tid + i * 256;     // 0..1023
            int m = e >> 4;            // 0..63
            int k = e & 15;            // 0..15
            As[k][m] = A[(size_t)(m0 + m) * K + kt + k];
            Ws[k][m] = W[(size_t)(n0 + m) * K + kt + k];
        }
        __syncthreads();
        #pragma unroll
        for (int k = 0; k < 16; ++k) {
            float a[4], b[4];
            #pragma unroll
            for (int i = 0; i < 4; ++i) a[i] = As[k][ty * 4 + i];
            #pragma unroll
            for (int j = 0; j < 4; ++j) b[j] = Ws[k][tx * 4 + j];
            #pragma unroll
            for (int i = 0; i < 4; ++i)
                #pragma unroll
                for (int j = 0; j < 4; ++j)
                    acc[i][j] += a[i] * b[j];
        }
        __syncthreads();
    }

    // Epilogue
    float* Cp;
    int ldc, ncol;
    if (mode == 2) {
        int seg = n0 >> 10;                   // 0:q 1:k 2:v (n0 multiple of 64)
        Cp   = (seg == 0) ? C : ((seg == 1) ? Ck : Cv);
        ncol = n0 & 1023;
        ldc  = DD;
    } else {
        Cp   = C;
        ncol = n0;
        ldc  = N;
    }

    #pragma unroll
    for (int i = 0; i < 4; ++i) {
        int m = m0 + ty * 4 + i;
        float r[4];
        #pragma unroll
        for (int j = 0; j < 4; ++j) {
            float v = acc[i][j] + bias[n0 + tx * 4 + j];
            if (mode == 1) v = fmaxf(v, 0.f);
            r[j] = v;
        }
        float4 v4 = make_float4(r[0], r[1], r[2], r[3]);
        *(float4*)(&Cp[(size_t)m * ldc + ncol + tx * 4]) = v4;
    }
}

// ---------------------------------------------------------------------------
// Causal attention, one wave (64 threads) per (b, h, q-row). Online softmax.
// Q: [B,S,D] (pre-scaled here by 1/8), K/V: [B,S,D] slices of the caches.
// ctx out: [B,S,D] head-merged.
// ---------------------------------------------------------------------------
__global__ __launch_bounds__(64)
void attn_kernel(const float* __restrict__ Qb, const float* __restrict__ Kb,
                 const float* __restrict__ Vb, float* __restrict__ ctx)
{
    const int qidx = blockIdx.x;   // 0..S-1
    const int h    = blockIdx.y;   // 0..H-1
    const int b    = blockIdx.z;   // 0..B-1
    const int lane = threadIdx.x;  // 0..63

    __shared__ float qs[64];
    __shared__ float Ks[64][65];   // padded: stride 65 -> bank = (row+col)%32, 2-way free
    __shared__ float ps[64];

    const float* qptr = Qb + ((size_t)(b * SS + qidx)) * DD + h * HD;
    qs[lane] = qptr[lane] * 0.125f;   // 1/sqrt(64)

    float m_run = -INFINITY;
    float l_run = 0.f;
    float acc   = 0.f;

    const int nchunk = qidx / 64 + 1;
    for (int c = 0; c < nchunk; ++c) {
        __syncthreads();   // protect Ks/ps reuse (also fences qs on c==0)
        const float* kbase = Kb + ((size_t)(b * SS + c * 64)) * DD + h * HD;
        for (int r = 0; r < 64; ++r)
            Ks[r][lane] = kbase[(size_t)r * DD + lane];
        __syncthreads();

        const int j = c * 64 + lane;
        float s_val = -INFINITY;
        if (j <= qidx) {
            float sv = 0.f;
            #pragma unroll
            for (int d = 0; d < 64; ++d) sv += qs[d] * Ks[lane][d];
            s_val = sv;
        }
        // wave max
        float cm = s_val;
        #pragma unroll
        for (int off = 32; off; off >>= 1) cm = fmaxf(cm, __shfl_xor(cm, off));
        float m_new = fmaxf(m_run, cm);
        float p = (j <= qidx) ? __expf(s_val - m_new) : 0.f;
        float csum = p;
        #pragma unroll
        for (int off = 32; off; off >>= 1) csum += __shfl_xor(csum, off);
        float scale = (m_run == -INFINITY) ? 0.f : __expf(m_run - m_new);
        l_run = l_run * scale + csum;
        m_run = m_new;
        ps[lane] = p;
        __syncthreads();

        const float* vbase = Vb + ((size_t)(b * SS + c * 64)) * DD + h * HD;
        float a2 = acc * scale;
        for (int jj = 0; jj < 64; ++jj)
            a2 += ps[jj] * vbase[(size_t)jj * DD + lane];
        acc = a2;
    }

    ctx[((size_t)(b * SS + qidx)) * DD + h * HD + lane] = acc / l_run;
}

// ---------------------------------------------------------------------------
// x = LayerNorm(x + add) * w + b   (row = D=1024, block 256, 4 elems/thread)
// ---------------------------------------------------------------------------
__global__ __launch_bounds__(256)
void ln_kernel(float* __restrict__ x, const float* __restrict__ add,
               const float* __restrict__ w, const float* __restrict__ b)
{
    const int row = blockIdx.x;
    const int t   = threadIdx.x;
    float* xr = x + (size_t)row * DD;
    const float* ar = add + (size_t)row * DD;

    float z[4];
    float s = 0.f, ss = 0.f;
    #pragma unroll
    for (int i = 0; i < 4; ++i) {
        int d = t + i * 256;
        z[i] = xr[d] + ar[d];
        s  += z[i];
        ss += z[i] * z[i];
    }
    #pragma unroll
    for (int off = 32; off; off >>= 1) {
        s  += __shfl_down(s, off);
        ss += __shfl_down(ss, off);
    }
    __shared__ float sbuf[4], ssbuf[4];
    const int wave = t >> 6, lane = t & 63;
    if (lane == 0) { sbuf[wave] = s; ssbuf[wave] = ss; }
    __syncthreads();
    if (t == 0) {
        float S = 0.f, SSum = 0.f;
        #pragma unroll
        for (int i = 0; i < 4; ++i) { S += sbuf[i]; SSum += ssbuf[i]; }
        float mean = S * (1.f / 1024.f);
        float var  = SSum * (1.f / 1024.f) - mean * mean;
        sbuf[0]  = mean;
        ssbuf[0] = rsqrtf(var + 1e-5f);
    }
    __syncthreads();
    const float mean = sbuf[0], rstd = ssbuf[0];
    #pragma unroll
    for (int i = 0; i < 4; ++i) {
        int d = t + i * 256;
        xr[d] = (z[i] - mean) * rstd * w[d] + b[d];
    }
}

// ---------------------------------------------------------------------------
extern "C" void kernel_launch(void* const* d_in, const int* in_sizes, int n_in,
                              void* d_out, int out_size, void* d_ws, size_t ws_size,
                              hipStream_t stream)
{
    const float* x_in  = (const float*)d_in[0];
    // d_in[1] = attn_mask (causal, unused: we apply causality analytically)
    const float* qkv_w = (const float*)d_in[2];
    const float* qkv_b = (const float*)d_in[3];
    const float* out_w = (const float*)d_in[4];
    const float* out_b = (const float*)d_in[5];
    const float* w1    = (const float*)d_in[6];
    const float* b1    = (const float*)d_in[7];
    const float* w2    = (const float*)d_in[8];
    const float* b2    = (const float*)d_in[9];
    const float* ln1w  = (const float*)d_in[10];
    const float* ln1b  = (const float*)d_in[11];
    const float* ln2w  = (const float*)d_in[12];
    const float* ln2b  = (const float*)d_in[13];

    float* out_x = (float*)d_out;                    // [B,S,D]
    float* out_k = out_x + (size_t)BSD;              // [L,B,S,D]
    float* out_v = out_k + (size_t)LL * BSD;         // [L,B,S,D]

    float* ws   = (float*)d_ws;
    float* xbuf = ws;                                // [B,S,D] running activations
    float* qbuf = ws + (size_t)BSD;                  // [B,S,D] q
    float* ctx  = ws + 2 * (size_t)BSD;              // [B,S,D] attention context
    float* proj = ws + 3 * (size_t)BSD;              // [B,S,D] proj / mlp out
    float* hbuf = ws + 4 * (size_t)BSD;              // [B,S,FF]

    hipMemcpyAsync(xbuf, x_in, (size_t)BSD * sizeof(float),
                   hipMemcpyDeviceToDevice, stream);

    const int M = BB * SS;   // 2048

    for (int l = 0; l < LL; ++l) {
        const float* qw  = qkv_w + (size_t)l * 3 * DD * DD;
        const float* qb  = qkv_b + (size_t)l * 3 * DD;
        const float* ow  = out_w + (size_t)l * DD * DD;
        const float* ob  = out_b + (size_t)l * DD;
        const float* w1l = w1    + (size_t)l * FFD * DD;
        const float* b1l = b1    + (size_t)l * FFD;
        const float* w2l = w2    + (size_t)l * DD * FFD;
        const float* b2l = b2    + (size_t)l * DD;
        float* kc = out_k + (size_t)l * BSD;
        float* vc = out_v + (size_t)l * BSD;

        // 1. fused QKV projection; k,v written straight into the caches
        gemm_kernel<<<dim3(3 * DD / 64, M / 64), 256, 0, stream>>>(
            xbuf, qw, qb, qbuf, kc, vc, M, 3 * DD, DD, 2);

        // 2. causal attention
        attn_kernel<<<dim3(SS, HH, BB), 64, 0, stream>>>(qbuf, kc, vc, ctx);

        // 3. output projection
        gemm_kernel<<<dim3(DD / 64, M / 64), 256, 0, stream>>>(
            ctx, ow, ob, proj, nullptr, nullptr, M, DD, DD, 0);

        // 4. x = LN(x + attn)
        ln_kernel<<<M, 256, 0, stream>>>(xbuf, proj,
                                         ln1w + (size_t)l * DD, ln1b + (size_t)l * DD);

        // 5. h = relu(x @ w1^T + b1)
        gemm_kernel<<<dim3(FFD / 64, M / 64), 256, 0, stream>>>(
            xbuf, w1l, b1l, hbuf, nullptr, nullptr, M, FFD, DD, 1);

        // 6. mlp = h @ w2^T + b2
        gemm_kernel<<<dim3(DD / 64, M / 64), 256, 0, stream>>>(
            hbuf, w2l, b2l, proj, nullptr, nullptr, M, DD, FFD, 0);

        // 7. x = LN(x + mlp)
        ln_kernel<<<M, 256, 0, stream>>>(xbuf, proj,
                                         ln2w + (size_t)l * DD, ln2b + (size_t)l * DD);
    }

    hipMemcpyAsync(out_x, xbuf, (size_t)BSD * sizeof(float),
                   hipMemcpyDeviceToDevice, stream);
}

// Round 2
// 4324.923 us; speedup vs baseline: 2.1611x; 2.1611x over previous
//
#include <hip/hip_runtime.h>
#include <cstdint>
#include <cstddef>
#include <math.h>

// Problem dims (fixed)
#define LL  8
#define BB  2
#define SS  1024
#define DD  1024
#define HH  16
#define HD  64
#define FFD 4096
#define BSD (BB*SS*DD)   // 2,097,152

typedef __attribute__((ext_vector_type(4))) float f32x4;
typedef __attribute__((ext_vector_type(8))) short bf16x8;

__device__ __forceinline__ unsigned short f2bf(float f) {
    unsigned u = __float_as_uint(f);
    unsigned r = (u + 0x7fffu + ((u >> 16) & 1u)) >> 16;   // RTN-even
    return (unsigned short)r;
}

#define GLD16(gsrc, ldst) \
    __builtin_amdgcn_global_load_lds((const __attribute__((address_space(1))) void*)(gsrc), \
                                     (__attribute__((address_space(3))) void*)(ldst), 16, 0, 0)

// ---------------------------------------------------------------------------
// f32 -> bf16 elementwise convert (n multiple of 1024; 4 elems/thread)
// ---------------------------------------------------------------------------
__global__ __launch_bounds__(256)
void cvt_bf16(const float* __restrict__ in, unsigned short* __restrict__ out)
{
    size_t i = (size_t)blockIdx.x * 256 + threadIdx.x;
    float4 v = *(const float4*)(in + i * 4);
    ushort4 o;
    o.x = f2bf(v.x); o.y = f2bf(v.y); o.z = f2bf(v.z); o.w = f2bf(v.w);
    *(ushort4*)(out + i * 4) = o;
}

// ---------------------------------------------------------------------------
// bf16 MFMA GEMM (m97 structure): C[M,N] = A[M,K] * W[N,K]^T + bias
// 128x128 tile, BK=32, 256 threads = 4 waves (2x2), 4x4 frags of 16x16x32.
// mode 0: f32 out C (ldc=N)
// mode 1: relu, bf16 out Cb (ldc=N)
// mode 2: QKV split: col seg 0->C(q f32), 1->Ck, 2->Cv, ldc=DD
// ---------------------------------------------------------------------------
__global__ __launch_bounds__(256)
void gemm_bf16(const unsigned short* __restrict__ A, const unsigned short* __restrict__ W,
               const float* __restrict__ bias,
               float* __restrict__ C, unsigned short* __restrict__ Cb,
               float* __restrict__ Ck, float* __restrict__ Cv,
               int M, int N, int K, int mode)
{
    __shared__ unsigned short As[128 * 32];
    __shared__ unsigned short Ws[128 * 32];

    const int tid  = threadIdx.x;
    const int m0   = blockIdx.y * 128;
    const int n0   = blockIdx.x * 128;
    const int lane = tid & 63;
    const int w    = tid >> 6;
    const int wr   = w >> 1, wc = w & 1;
    const int lr   = lane & 15;         // fragment row (A) / col (B) / col (C)
    const int kq   = lane >> 4;         // 0..3: k-group of 8 (in), row-group of 4 (out)

    f32x4 acc[4][4];
    #pragma unroll
    for (int i = 0; i < 4; ++i)
        #pragma unroll
        for (int j = 0; j < 4; ++j) {
            f32x4 z = {0.f, 0.f, 0.f, 0.f};
            acc[i][j] = z;
        }

    for (int kt = 0; kt < K; kt += 32) {
        if (kt) __syncthreads();
        #pragma unroll
        for (int i = 0; i < 2; ++i) {
            int idx = i * 256 + tid;         // 0..511
            int row = idx >> 2;              // 0..127
            int kp  = idx & 3;               // 16B chunk within 64B row
            GLD16(A + (size_t)(m0 + row) * K + kt + kp * 8, As + idx * 8);
            GLD16(W + (size_t)(n0 + row) * K + kt + kp * 8, Ws + idx * 8);
        }
        __syncthreads();

        bf16x8 a[4], b[4];
        #pragma unroll
        for (int fi = 0; fi < 4; ++fi)
            a[fi] = *(const bf16x8*)(As + (wr * 64 + fi * 16 + lr) * 32 + kq * 8);
        #pragma unroll
        for (int fj = 0; fj < 4; ++fj)
            b[fj] = *(const bf16x8*)(Ws + (wc * 64 + fj * 16 + lr) * 32 + kq * 8);
        #pragma unroll
        for (int fi = 0; fi < 4; ++fi)
            #pragma unroll
            for (int fj = 0; fj < 4; ++fj)
                acc[fi][fj] = __builtin_amdgcn_mfma_f32_16x16x32_bf16(
                    a[fi], b[fj], acc[fi][fj], 0, 0, 0);
    }

    // Epilogue. C/D layout: col = lane&15, row = (lane>>4)*4 + reg
    const int seg = n0 >> 10;
    #pragma unroll
    for (int fj = 0; fj < 4; ++fj) {
        const int cl = wc * 64 + fj * 16 + lr;     // 0..127
        const float bv = bias[n0 + cl];
        #pragma unroll
        for (int fi = 0; fi < 4; ++fi) {
            #pragma unroll
            for (int r = 0; r < 4; ++r) {
                const int row = m0 + wr * 64 + fi * 16 + kq * 4 + r;
                const float val = acc[fi][fj][r] + bv;
                if (mode == 2) {
                    float* dst = (seg == 0) ? C : ((seg == 1) ? Ck : Cv);
                    dst[(size_t)row * DD + (n0 & 1023) + cl] = val;
                } else if (mode == 1) {
                    Cb[(size_t)row * N + n0 + cl] = f2bf(fmaxf(val, 0.f));
                } else {
                    C[(size_t)row * N + n0 + cl] = val;
                }
            }
        }
    }
}

// ---------------------------------------------------------------------------
// Tiled causal attention. Block = (b, h, 64 q-rows), 256 threads.
// Thread t: q-row = t>>2, d/k-quarter = t&3. Q in regs, K^T/V/P in LDS.
// Softmax reduce across the 4-lane quarter group via __shfl_xor(1,2).
// Output written directly as bf16 (feeds out-proj GEMM).
// ---------------------------------------------------------------------------
__global__ __launch_bounds__(256)
void attn_kernel(const float* __restrict__ Qb, const float* __restrict__ Kb,
                 const float* __restrict__ Vb, unsigned short* __restrict__ ctxb)
{
    const int qt = blockIdx.x;      // q-tile 0..15
    const int h  = blockIdx.y;
    const int b  = blockIdx.z;
    const int t  = threadIdx.x;
    const int q    = t >> 2;        // 0..63 local q row
    const int quar = t & 3;         // 0..3

    __shared__ float KsT[64][68];   // [d][k]  (stride 272B: 16B-aligned rows)
    __shared__ float Vs[64][68];    // [k][d]
    __shared__ float Ps[64][65];    // [q][k]  (scalar access)

    const int qg = qt * 64 + q;

    // Q row into registers, pre-scaled by 1/sqrt(64)
    float qreg[64];
    const float* qp = Qb + ((size_t)(b * SS + qg)) * DD + h * HD;
    #pragma unroll
    for (int i = 0; i < 16; ++i) {
        float4 v = *(const float4*)(qp + i * 4);
        qreg[i * 4 + 0] = v.x * 0.125f;
        qreg[i * 4 + 1] = v.y * 0.125f;
        qreg[i * 4 + 2] = v.z * 0.125f;
        qreg[i * 4 + 3] = v.w * 0.125f;
    }

    float m_run = -INFINITY, l_run = 0.f;
    float acc[16];
    #pragma unroll
    for (int i = 0; i < 16; ++i) acc[i] = 0.f;

    const int nch = qt + 1;
    for (int c = 0; c < nch; ++c) {
        __syncthreads();   // previous chunk's Vs/Ps reads done
        const float* kb = Kb + ((size_t)(b * SS + c * 64)) * DD + h * HD;
        const float* vb = Vb + ((size_t)(b * SS + c * 64)) * DD + h * HD;
        #pragma unroll
        for (int i = 0; i < 4; ++i) {
            int e  = i * 256 + t;     // 0..1023
            int r  = e >> 4;          // k row 0..63
            int d4 = e & 15;          // float4 within row
            float4 kv = *(const float4*)(kb + (size_t)r * DD + d4 * 4);
            KsT[d4 * 4 + 0][r] = kv.x;
            KsT[d4 * 4 + 1][r] = kv.y;
            KsT[d4 * 4 + 2][r] = kv.z;
            KsT[d4 * 4 + 3][r] = kv.w;
            float4 vv = *(const float4*)(vb + (size_t)r * DD + d4 * 4);
            *(float4*)&Vs[r][d4 * 4] = vv;
        }
        __syncthreads();

        // scores for k in [quar*16, quar*16+16)
        float s[16];
        #pragma unroll
        for (int kk = 0; kk < 16; ++kk) s[kk] = 0.f;
        #pragma unroll
        for (int d = 0; d < 64; ++d) {
            const float qd = qreg[d];
            #pragma unroll
            for (int c4 = 0; c4 < 4; ++c4) {
                float4 kv = *(const float4*)&KsT[d][quar * 16 + c4 * 4];
                s[c4 * 4 + 0] += qd * kv.x;
                s[c4 * 4 + 1] += qd * kv.y;
                s[c4 * 4 + 2] += qd * kv.z;
                s[c4 * 4 + 3] += qd * kv.w;
            }
        }
        if (c == qt) {   // diagonal chunk: causal mask
            #pragma unroll
            for (int kk = 0; kk < 16; ++kk) {
                int kg = c * 64 + quar * 16 + kk;
                if (kg > qg) s[kk] = -INFINITY;
            }
        }
        // row max across 16 local + 4-lane group
        float mx = s[0];
        #pragma unroll
        for (int kk = 1; kk < 16; ++kk) mx = fmaxf(mx, s[kk]);
        mx = fmaxf(mx, __shfl_xor(mx, 1));
        mx = fmaxf(mx, __shfl_xor(mx, 2));
        const float m_new = fmaxf(m_run, mx);

        float p[16], ls = 0.f;
        #pragma unroll
        for (int kk = 0; kk < 16; ++kk) {
            p[kk] = __expf(s[kk] - m_new);
            ls += p[kk];
        }
        ls += __shfl_xor(ls, 1);
        ls += __shfl_xor(ls, 2);
        const float scale = __expf(m_run - m_new);   // exp(-inf)=0 on first chunk
        l_run = l_run * scale + ls;
        m_run = m_new;
        #pragma unroll
        for (int i = 0; i < 16; ++i) acc[i] *= scale;
        #pragma unroll
        for (int kk = 0; kk < 16; ++kk) Ps[q][quar * 16 + kk] = p[kk];
        __syncthreads();

        // PV: out dims d in [quar*16, quar*16+16)
        #pragma unroll 4
        for (int k = 0; k < 64; ++k) {
            const float pv = Ps[q][k];
            #pragma unroll
            for (int c4 = 0; c4 < 4; ++c4) {
                float4 vv = *(const float4*)&Vs[k][quar * 16 + c4 * 4];
                acc[c4 * 4 + 0] += pv * vv.x;
                acc[c4 * 4 + 1] += pv * vv.y;
                acc[c4 * 4 + 2] += pv * vv.z;
                acc[c4 * 4 + 3] += pv * vv.w;
            }
        }
    }

    const float inv = 1.f / l_run;
    unsigned short* op = ctxb + ((size_t)(b * SS + qg)) * DD + h * HD + quar * 16;
    #pragma unroll
    for (int i = 0; i < 16; ++i) op[i] = f2bf(acc[i] * inv);
}

// ---------------------------------------------------------------------------
// x = LayerNorm(x + add) * w + b ; also writes bf16 copy for next GEMM
// ---------------------------------------------------------------------------
__global__ __launch_bounds__(256)
void ln_kernel(float* __restrict__ x, const float* __restrict__ add,
               const float* __restrict__ w, const float* __restrict__ b,
               unsigned short* __restrict__ xb)
{
    const int row = blockIdx.x;
    const int t   = threadIdx.x;
    float* xr = x + (size_t)row * DD;
    const float* ar = add + (size_t)row * DD;
    unsigned short* xbr = xb + (size_t)row * DD;

    float z[4];
    float s = 0.f, ss = 0.f;
    #pragma unroll
    for (int i = 0; i < 4; ++i) {
        int d = t + i * 256;
        z[i] = xr[d] + ar[d];
        s  += z[i];
        ss += z[i] * z[i];
    }
    #pragma unroll
    for (int off = 32; off; off >>= 1) {
        s  += __shfl_down(s, off);
        ss += __shfl_down(ss, off);
    }
    __shared__ float sbuf[4], ssbuf[4];
    const int wave = t >> 6, lane = t & 63;
    if (lane == 0) { sbuf[wave] = s; ssbuf[wave] = ss; }
    __syncthreads();
    if (t == 0) {
        float S = 0.f, SSum = 0.f;
        #pragma unroll
        for (int i = 0; i < 4; ++i) { S += sbuf[i]; SSum += ssbuf[i]; }
        float mean = S * (1.f / 1024.f);
        float var  = SSum * (1.f / 1024.f) - mean * mean;
        sbuf[0]  = mean;
        ssbuf[0] = rsqrtf(var + 1e-5f);
    }
    __syncthreads();
    const float mean = sbuf[0], rstd = ssbuf[0];
    #pragma unroll
    for (int i = 0; i < 4; ++i) {
        int d = t + i * 256;
        float v = (z[i] - mean) * rstd * w[d] + b[d];
        xr[d]  = v;
        xbr[d] = f2bf(v);
    }
}

// ---------------------------------------------------------------------------
extern "C" void kernel_launch(void* const* d_in, const int* in_sizes, int n_in,
                              void* d_out, int out_size, void* d_ws, size_t ws_size,
                              hipStream_t stream)
{
    const float* x_in  = (const float*)d_in[0];
    const float* qkv_w = (const float*)d_in[2];
    const float* qkv_b = (const float*)d_in[3];
    const float* out_w = (const float*)d_in[4];
    const float* out_b = (const float*)d_in[5];
    const float* w1    = (const float*)d_in[6];
    const float* b1    = (const float*)d_in[7];
    const float* w2    = (const float*)d_in[8];
    const float* b2    = (const float*)d_in[9];
    const float* ln1w  = (const float*)d_in[10];
    const float* ln1b  = (const float*)d_in[11];
    const float* ln2w  = (const float*)d_in[12];
    const float* ln2b  = (const float*)d_in[13];

    float* out_x = (float*)d_out;                    // [B,S,D]
    float* out_k = out_x + (size_t)BSD;              // [L,B,S,D]
    float* out_v = out_k + (size_t)LL * BSD;         // [L,B,S,D]

    const size_t MEG = 1024 * 1024;
    float* ws   = (float*)d_ws;
    float*          xbuf = ws;                              // 2M f32
    float*          qbuf = ws + 2 * MEG;                    // 2M f32
    float*          proj = ws + 4 * MEG;                    // 2M f32
    unsigned short* xb16 = (unsigned short*)(ws + 6 * MEG); // 2M bf16
    unsigned short* ctxb = (unsigned short*)(ws + 7 * MEG); // 2M bf16
    unsigned short* hb16 = (unsigned short*)(ws + 8 * MEG); // 8M bf16 (16 MB)
    unsigned short* wS   = (unsigned short*)(ws + 12 * MEG);// up to 4M bf16 (8 MB)

    hipMemcpyAsync(xbuf, x_in, (size_t)BSD * sizeof(float),
                   hipMemcpyDeviceToDevice, stream);
    cvt_bf16<<<BSD / 1024, 256, 0, stream>>>(x_in, xb16);

    const int M = BB * SS;   // 2048

    for (int l = 0; l < LL; ++l) {
        const float* qw  = qkv_w + (size_t)l * 3 * DD * DD;
        const float* qb  = qkv_b + (size_t)l * 3 * DD;
        const float* ow  = out_w + (size_t)l * DD * DD;
        const float* ob  = out_b + (size_t)l * DD;
        const float* w1l = w1    + (size_t)l * FFD * DD;
        const float* b1l = b1    + (size_t)l * FFD;
        const float* w2l = w2    + (size_t)l * DD * FFD;
        const float* b2l = b2    + (size_t)l * DD;
        float* kc = out_k + (size_t)l * BSD;
        float* vc = out_v + (size_t)l * BSD;

        // 1. QKV projection (fused); k,v straight into caches (f32)
        cvt_bf16<<<3 * DD * DD / 1024, 256, 0, stream>>>(qw, wS);
        gemm_bf16<<<dim3(3 * DD / 128, M / 128), 256, 0, stream>>>(
            xb16, wS, qb, qbuf, nullptr, kc, vc, M, 3 * DD, DD, 2);

        // 2. causal attention -> bf16 ctx
        attn_kernel<<<dim3(SS / 64, HH, BB), 256, 0, stream>>>(qbuf, kc, vc, ctxb);

        // 3. output projection -> proj f32
        cvt_bf16<<<DD * DD / 1024, 256, 0, stream>>>(ow, wS);
        gemm_bf16<<<dim3(DD / 128, M / 128), 256, 0, stream>>>(
            ctxb, wS, ob, proj, nullptr, nullptr, nullptr, M, DD, DD, 0);

        // 4. x = LN(x + attn)
        ln_kernel<<<M, 256, 0, stream>>>(xbuf, proj,
                                         ln1w + (size_t)l * DD, ln1b + (size_t)l * DD, xb16);

        // 5. h = relu(x @ w1^T + b1) -> bf16
        cvt_bf16<<<FFD * DD / 1024, 256, 0, stream>>>(w1l, wS);
        gemm_bf16<<<dim3(FFD / 128, M / 128), 256, 0, stream>>>(
            xb16, wS, b1l, nullptr, hb16, nullptr, nullptr, M, FFD, DD, 1);

        // 6. mlp = h @ w2^T + b2 -> proj f32
        cvt_bf16<<<DD * FFD / 1024, 256, 0, stream>>>(w2l, wS);
        gemm_bf16<<<dim3(DD / 128, M / 128), 256, 0, stream>>>(
            hb16, wS, b2l, proj, nullptr, nullptr, nullptr, M, DD, FFD, 0);

        // 7. x = LN(x + mlp)
        ln_kernel<<<M, 256, 0, stream>>>(xbuf, proj,
                                         ln2w + (size_t)l * DD, ln2b + (size_t)l * DD, xb16);
    }

    hipMemcpyAsync(out_x, xbuf, (size_t)BSD * sizeof(float),
                   hipMemcpyDeviceToDevice, stream);
}

// Round 3
// 1942.372 us; speedup vs baseline: 4.8120x; 2.2266x over previous
//
#include <hip/hip_runtime.h>
#include <cstdint>
#include <cstddef>
#include <math.h>

// Problem dims (fixed)
#define LL  8
#define BB  2
#define SS  1024
#define DD  1024
#define HH  16
#define HD  64
#define FFD 4096
#define BSD (BB*SS*DD)   // 2,097,152

typedef __attribute__((ext_vector_type(4))) float f32x4;
typedef __attribute__((ext_vector_type(8))) short bf16x8;
typedef __attribute__((ext_vector_type(4))) short bf16x4;

__device__ __forceinline__ unsigned short f2bf(float f) {
    unsigned u = __float_as_uint(f);
    unsigned r = (u + 0x7fffu + ((u >> 16) & 1u)) >> 16;   // RTN-even
    return (unsigned short)r;
}

#define GLD16(gsrc, ldst) \
    __builtin_amdgcn_global_load_lds((const __attribute__((address_space(1))) void*)(gsrc), \
                                     (__attribute__((address_space(3))) void*)(ldst), 16, 0, 0)

// ---------------------------------------------------------------------------
// f32 -> bf16 elementwise convert (n multiple of 1024; 4 elems/thread)
// ---------------------------------------------------------------------------
__global__ __launch_bounds__(256)
void cvt_bf16(const float* __restrict__ in, unsigned short* __restrict__ out)
{
    size_t i = (size_t)blockIdx.x * 256 + threadIdx.x;
    float4 v = *(const float4*)(in + i * 4);
    ushort4 o;
    o.x = f2bf(v.x); o.y = f2bf(v.y); o.z = f2bf(v.z); o.w = f2bf(v.w);
    *(ushort4*)(out + i * 4) = o;
}

// ---------------------------------------------------------------------------
// bf16 MFMA GEMM (m97 structure): C[M,N] = A[M,K] * W[N,K]^T + bias
// 128x128 tile, BK=32, 256 threads = 4 waves (2x2), 4x4 frags of 16x16x32.
// mode 0: f32 out C (ldc=N)
// mode 1: relu, bf16 out Cb (ldc=N)
// mode 2: QKV split: seg0 -> Cb(q bf16); seg1 -> Ck f32 + Kb16; seg2 -> Cv f32 + Vb16
// ---------------------------------------------------------------------------
__global__ __launch_bounds__(256)
void gemm_bf16(const unsigned short* __restrict__ A, const unsigned short* __restrict__ W,
               const float* __restrict__ bias,
               float* __restrict__ C, unsigned short* __restrict__ Cb,
               float* __restrict__ Ck, float* __restrict__ Cv,
               unsigned short* __restrict__ Kb16, unsigned short* __restrict__ Vb16,
               int M, int N, int K, int mode)
{
    __shared__ unsigned short As[128 * 32];
    __shared__ unsigned short Ws[128 * 32];

    const int tid  = threadIdx.x;
    const int m0   = blockIdx.y * 128;
    const int n0   = blockIdx.x * 128;
    const int lane = tid & 63;
    const int w    = tid >> 6;
    const int wr   = w >> 1, wc = w & 1;
    const int lr   = lane & 15;
    const int kq   = lane >> 4;

    f32x4 acc[4][4];
    #pragma unroll
    for (int i = 0; i < 4; ++i)
        #pragma unroll
        for (int j = 0; j < 4; ++j) {
            f32x4 z = {0.f, 0.f, 0.f, 0.f};
            acc[i][j] = z;
        }

    for (int kt = 0; kt < K; kt += 32) {
        if (kt) __syncthreads();
        #pragma unroll
        for (int i = 0; i < 2; ++i) {
            int idx = i * 256 + tid;
            int row = idx >> 2;
            int kp  = idx & 3;
            GLD16(A + (size_t)(m0 + row) * K + kt + kp * 8, As + idx * 8);
            GLD16(W + (size_t)(n0 + row) * K + kt + kp * 8, Ws + idx * 8);
        }
        __syncthreads();

        bf16x8 a[4], b[4];
        #pragma unroll
        for (int fi = 0; fi < 4; ++fi)
            a[fi] = *(const bf16x8*)(As + (wr * 64 + fi * 16 + lr) * 32 + kq * 8);
        #pragma unroll
        for (int fj = 0; fj < 4; ++fj)
            b[fj] = *(const bf16x8*)(Ws + (wc * 64 + fj * 16 + lr) * 32 + kq * 8);
        #pragma unroll
        for (int fi = 0; fi < 4; ++fi)
            #pragma unroll
            for (int fj = 0; fj < 4; ++fj)
                acc[fi][fj] = __builtin_amdgcn_mfma_f32_16x16x32_bf16(
                    a[fi], b[fj], acc[fi][fj], 0, 0, 0);
    }

    const int seg = n0 >> 10;
    #pragma unroll
    for (int fj = 0; fj < 4; ++fj) {
        const int cl = wc * 64 + fj * 16 + lr;
        const float bv = bias[n0 + cl];
        #pragma unroll
        for (int fi = 0; fi < 4; ++fi) {
            #pragma unroll
            for (int r = 0; r < 4; ++r) {
                const int row = m0 + wr * 64 + fi * 16 + kq * 4 + r;
                const float val = acc[fi][fj][r] + bv;
                if (mode == 2) {
                    const int col = (n0 & 1023) + cl;
                    float* dstf = (seg == 1) ? Ck : ((seg == 2) ? Cv : nullptr);
                    unsigned short* dstb = (seg == 0) ? Cb : ((seg == 1) ? Kb16 : Vb16);
                    if (dstf) dstf[(size_t)row * DD + col] = val;
                    dstb[(size_t)row * DD + col] = f2bf(val);
                } else if (mode == 1) {
                    Cb[(size_t)row * N + n0 + cl] = f2bf(fmaxf(val, 0.f));
                } else {
                    C[(size_t)row * N + n0 + cl] = val;
                }
            }
        }
    }
}

// ---------------------------------------------------------------------------
// MFMA causal flash attention. Block = (64 q-rows, h, b), 256 thr = 4 waves.
// Wave w owns q rows [w*16, w*16+16). Per 64-key chunk:
//   stage K [64][68] bf16 + V transposed Vt[d][k] [64][68] bf16 in LDS;
//   QK^T via mfma_16x16x32 (A=Q regs, B=K rows), scale+mask, shfl softmax,
//   P -> bf16 -> per-wave LDS, PV via mfma (A=P, B=Vt rows).
// Stride 68 shorts (136B) rows: all b64 LDS accesses <=2-way (free).
// ---------------------------------------------------------------------------
__global__ __launch_bounds__(256)
void attn_mfma(const unsigned short* __restrict__ Qb, const unsigned short* __restrict__ Kb,
               const unsigned short* __restrict__ Vb, unsigned short* __restrict__ ctxb)
{
    const int qt = blockIdx.x;      // q-tile 0..15
    const int h  = blockIdx.y;
    const int b  = blockIdx.z;
    const int tid  = threadIdx.x;
    const int lane = tid & 63;
    const int w    = tid >> 6;
    const int lr   = lane & 15;
    const int hi   = lane >> 4;

    __shared__ unsigned short smem[(64 + 64 + 4 * 16) * 68];
    unsigned short* Ks = smem;                         // [64][68] (key-major)
    unsigned short* Vt = smem + 64 * 68;               // [64][68] (d-major, cols=k)
    unsigned short* Pl = smem + 128 * 68 + w * 16 * 68;// per-wave [16][68]

    // Q fragments, held across chunks: A-frag row = lr
    bf16x8 qa[2];
    {
        const unsigned short* qp =
            Qb + ((size_t)(b * SS + qt * 64 + w * 16 + lr)) * DD + h * HD;
        qa[0] = *(const bf16x8*)(qp + hi * 8);
        qa[1] = *(const bf16x8*)(qp + 32 + hi * 8);
    }

    f32x4 accO[4];
    #pragma unroll
    for (int t = 0; t < 4; ++t) { f32x4 z = {0.f,0.f,0.f,0.f}; accO[t] = z; }
    float m_run[4], l_run[4];
    #pragma unroll
    for (int r = 0; r < 4; ++r) { m_run[r] = -INFINITY; l_run[r] = 0.f; }

    for (int c = 0; c <= qt; ++c) {
        __syncthreads();
        const unsigned short* kb = Kb + ((size_t)(b * SS + c * 64)) * DD + h * HD;
        const unsigned short* vb = Vb + ((size_t)(b * SS + c * 64)) * DD + h * HD;
        #pragma unroll
        for (int i = 0; i < 2; ++i) {
            // K: row-major copy
            int e  = tid + i * 256;       // 0..511
            int r  = e >> 3, ch = e & 7;
            bf16x8 kv = *(const bf16x8*)(kb + (size_t)r * DD + ch * 8);
            *(bf16x4*)(Ks + r * 68 + ch * 8)     = __builtin_shufflevector(kv, kv, 0,1,2,3);
            *(bf16x4*)(Ks + r * 68 + ch * 8 + 4) = __builtin_shufflevector(kv, kv, 4,5,6,7);
            // V: transposed scatter (conflict-free: k=lane spreads banks)
            int k  = e & 63, d0 = (e >> 6) * 8;
            bf16x8 vv = *(const bf16x8*)(vb + (size_t)k * DD + d0);
            #pragma unroll
            for (int j = 0; j < 8; ++j)
                Vt[(d0 + j) * 68 + k] = (unsigned short)vv[j];
        }
        __syncthreads();

        // QK^T: S[16q][64k], 4 k-tiles x 2 d-steps
        f32x4 sa[4];
        #pragma unroll
        for (int t = 0; t < 4; ++t) { f32x4 z = {0.f,0.f,0.f,0.f}; sa[t] = z; }
        #pragma unroll
        for (int t = 0; t < 4; ++t) {
            #pragma unroll
            for (int s = 0; s < 2; ++s) {
                const unsigned short* bp = Ks + (t * 16 + lr) * 68 + s * 32 + hi * 8;
                bf16x4 b0 = *(const bf16x4*)bp;
                bf16x4 b1 = *(const bf16x4*)(bp + 4);
                bf16x8 bb = __builtin_shufflevector(b0, b1, 0,1,2,3,4,5,6,7);
                sa[t] = __builtin_amdgcn_mfma_f32_16x16x32_bf16(qa[s], bb, sa[t], 0, 0, 0);
            }
        }
        // scale + causal mask (diagonal chunk only)
        #pragma unroll
        for (int t = 0; t < 4; ++t)
            #pragma unroll
            for (int r = 0; r < 4; ++r)
                sa[t][r] *= 0.125f;
        if (c == qt) {
            const int qg = w * 16 + hi * 4;   // + r ; kg = t*16 + lr (same 64-tile)
            #pragma unroll
            for (int t = 0; t < 4; ++t)
                #pragma unroll
                for (int r = 0; r < 4; ++r)
                    if (t * 16 + lr > qg + r) sa[t][r] = -1e30f;
        }
        // online softmax, per accumulator row r (4 q-rows/lane)
        #pragma unroll
        for (int r = 0; r < 4; ++r) {
            float mx = fmaxf(fmaxf(sa[0][r], sa[1][r]), fmaxf(sa[2][r], sa[3][r]));
            mx = fmaxf(mx, __shfl_xor(mx, 1));
            mx = fmaxf(mx, __shfl_xor(mx, 2));
            mx = fmaxf(mx, __shfl_xor(mx, 4));
            mx = fmaxf(mx, __shfl_xor(mx, 8));
            const float mn = fmaxf(m_run[r], mx);
            float sum = 0.f;
            #pragma unroll
            for (int t = 0; t < 4; ++t) {
                float p = __expf(sa[t][r] - mn);
                sa[t][r] = p;
                sum += p;
            }
            sum += __shfl_xor(sum, 1);
            sum += __shfl_xor(sum, 2);
            sum += __shfl_xor(sum, 4);
            sum += __shfl_xor(sum, 8);
            const float sc = __expf(m_run[r] - mn);
            l_run[r] = l_run[r] * sc + sum;
            m_run[r] = mn;
            #pragma unroll
            for (int t = 0; t < 4; ++t) accO[t][r] *= sc;
        }
        // P -> bf16 -> per-wave LDS (rows = q-local 4*hi+r, cols = k)
        #pragma unroll
        for (int t = 0; t < 4; ++t)
            #pragma unroll
            for (int r = 0; r < 4; ++r)
                Pl[(hi * 4 + r) * 68 + t * 16 + lr] = f2bf(sa[t][r]);

        // PV: accO[16q][64d] += P[16x64] * V[64x64]
        #pragma unroll
        for (int s = 0; s < 2; ++s) {
            const unsigned short* ap = Pl + lr * 68 + s * 32 + hi * 8;
            bf16x4 a0 = *(const bf16x4*)ap;
            bf16x4 a1 = *(const bf16x4*)(ap + 4);
            bf16x8 aa = __builtin_shufflevector(a0, a1, 0,1,2,3,4,5,6,7);
            #pragma unroll
            for (int t = 0; t < 4; ++t) {
                const unsigned short* bp = Vt + (t * 16 + lr) * 68 + s * 32 + hi * 8;
                bf16x4 b0 = *(const bf16x4*)bp;
                bf16x4 b1 = *(const bf16x4*)(bp + 4);
                bf16x8 bb = __builtin_shufflevector(b0, b1, 0,1,2,3,4,5,6,7);
                accO[t] = __builtin_amdgcn_mfma_f32_16x16x32_bf16(aa, bb, accO[t], 0, 0, 0);
            }
        }
    }

    // finalize + staged coalesced store
    float inv[4];
    #pragma unroll
    for (int r = 0; r < 4; ++r) inv[r] = 1.f / l_run[r];

    __syncthreads();
    float* Of = (float*)smem;   // [64][68] overlays Ks+Vt (17408 B)
    #pragma unroll
    for (int t = 0; t < 4; ++t)
        #pragma unroll
        for (int r = 0; r < 4; ++r)
            Of[(w * 16 + hi * 4 + r) * 68 + t * 16 + lr] = accO[t][r] * inv[r];
    __syncthreads();
    #pragma unroll
    for (int i = 0; i < 2; ++i) {
        int e = tid + i * 256;
        int r = e >> 3, ch = e & 7;
        const float* src = Of + r * 68 + ch * 8;
        float4 v0 = *(const float4*)(src);
        float4 v1 = *(const float4*)(src + 4);
        bf16x8 o;
        o[0] = (short)f2bf(v0.x); o[1] = (short)f2bf(v0.y);
        o[2] = (short)f2bf(v0.z); o[3] = (short)f2bf(v0.w);
        o[4] = (short)f2bf(v1.x); o[5] = (short)f2bf(v1.y);
        o[6] = (short)f2bf(v1.z); o[7] = (short)f2bf(v1.w);
        *(bf16x8*)(ctxb + ((size_t)(b * SS + qt * 64 + r)) * DD + h * HD + ch * 8) = o;
    }
}

// ---------------------------------------------------------------------------
// x = LayerNorm(x + add) * w + b ; also writes bf16 copy for next GEMM
// ---------------------------------------------------------------------------
__global__ __launch_bounds__(256)
void ln_kernel(float* __restrict__ x, const float* __restrict__ add,
               const float* __restrict__ w, const float* __restrict__ b,
               unsigned short* __restrict__ xb)
{
    const int row = blockIdx.x;
    const int t   = threadIdx.x;
    float* xr = x + (size_t)row * DD;
    const float* ar = add + (size_t)row * DD;
    unsigned short* xbr = xb + (size_t)row * DD;

    float z[4];
    float s = 0.f, ss = 0.f;
    #pragma unroll
    for (int i = 0; i < 4; ++i) {
        int d = t + i * 256;
        z[i] = xr[d] + ar[d];
        s  += z[i];
        ss += z[i] * z[i];
    }
    #pragma unroll
    for (int off = 32; off; off >>= 1) {
        s  += __shfl_down(s, off);
        ss += __shfl_down(ss, off);
    }
    __shared__ float sbuf[4], ssbuf[4];
    const int wave = t >> 6, lane = t & 63;
    if (lane == 0) { sbuf[wave] = s; ssbuf[wave] = ss; }
    __syncthreads();
    if (t == 0) {
        float S = 0.f, SSum = 0.f;
        #pragma unroll
        for (int i = 0; i < 4; ++i) { S += sbuf[i]; SSum += ssbuf[i]; }
        float mean = S * (1.f / 1024.f);
        float var  = SSum * (1.f / 1024.f) - mean * mean;
        sbuf[0]  = mean;
        ssbuf[0] = rsqrtf(var + 1e-5f);
    }
    __syncthreads();
    const float mean = sbuf[0], rstd = ssbuf[0];
    #pragma unroll
    for (int i = 0; i < 4; ++i) {
        int d = t + i * 256;
        float v = (z[i] - mean) * rstd * w[d] + b[d];
        xr[d]  = v;
        xbr[d] = f2bf(v);
    }
}

// ---------------------------------------------------------------------------
extern "C" void kernel_launch(void* const* d_in, const int* in_sizes, int n_in,
                              void* d_out, int out_size, void* d_ws, size_t ws_size,
                              hipStream_t stream)
{
    const float* x_in  = (const float*)d_in[0];
    const float* qkv_w = (const float*)d_in[2];
    const float* qkv_b = (const float*)d_in[3];
    const float* out_w = (const float*)d_in[4];
    const float* out_b = (const float*)d_in[5];
    const float* w1    = (const float*)d_in[6];
    const float* b1    = (const float*)d_in[7];
    const float* w2    = (const float*)d_in[8];
    const float* b2    = (const float*)d_in[9];
    const float* ln1w  = (const float*)d_in[10];
    const float* ln1b  = (const float*)d_in[11];
    const float* ln2w  = (const float*)d_in[12];
    const float* ln2b  = (const float*)d_in[13];

    float* out_x = (float*)d_out;                    // [B,S,D]
    float* out_k = out_x + (size_t)BSD;              // [L,B,S,D]
    float* out_v = out_k + (size_t)LL * BSD;         // [L,B,S,D]

    const size_t MEG = 1024 * 1024;
    float* ws = (float*)d_ws;
    float*          xbuf = ws;                               // 2M f32
    float*          proj = ws + 2 * MEG;                     // 2M f32
    unsigned short* xb16 = (unsigned short*)(ws + 4 * MEG);  // 2M bf16
    unsigned short* ctxb = (unsigned short*)(ws + 5 * MEG);  // 2M bf16
    unsigned short* wS   = (unsigned short*)(ws + 6 * MEG);  // 4M bf16 (8 MB)
    unsigned short* hb16 = (unsigned short*)(ws + 8 * MEG);  // 8M bf16 (16 MB)
    // q/k/v bf16 alias the hb16 region (lifetimes disjoint within a layer)
    unsigned short* qb16 = hb16;
    unsigned short* kb16 = hb16 + 2 * MEG;
    unsigned short* vb16 = hb16 + 4 * MEG;

    hipMemcpyAsync(xbuf, x_in, (size_t)BSD * sizeof(float),
                   hipMemcpyDeviceToDevice, stream);
    cvt_bf16<<<BSD / 1024, 256, 0, stream>>>(x_in, xb16);

    const int M = BB * SS;   // 2048

    for (int l = 0; l < LL; ++l) {
        const float* qw  = qkv_w + (size_t)l * 3 * DD * DD;
        const float* qb  = qkv_b + (size_t)l * 3 * DD;
        const float* ow  = out_w + (size_t)l * DD * DD;
        const float* ob  = out_b + (size_t)l * DD;
        const float* w1l = w1    + (size_t)l * FFD * DD;
        const float* b1l = b1    + (size_t)l * FFD;
        const float* w2l = w2    + (size_t)l * DD * FFD;
        const float* b2l = b2    + (size_t)l * DD;
        float* kc = out_k + (size_t)l * BSD;
        float* vc = out_v + (size_t)l * BSD;

        // 1. QKV projection; k,v -> f32 caches + bf16 copies; q -> bf16
        cvt_bf16<<<3 * DD * DD / 1024, 256, 0, stream>>>(qw, wS);
        gemm_bf16<<<dim3(3 * DD / 128, M / 128), 256, 0, stream>>>(
            xb16, wS, qb, nullptr, qb16, kc, vc, kb16, vb16, M, 3 * DD, DD, 2);

        // 2. MFMA causal attention -> bf16 ctx
        attn_mfma<<<dim3(SS / 64, HH, BB), 256, 0, stream>>>(qb16, kb16, vb16, ctxb);

        // 3. output projection -> proj f32
        cvt_bf16<<<DD * DD / 1024, 256, 0, stream>>>(ow, wS);
        gemm_bf16<<<dim3(DD / 128, M / 128), 256, 0, stream>>>(
            ctxb, wS, ob, proj, nullptr, nullptr, nullptr, nullptr, nullptr, M, DD, DD, 0);

        // 4. x = LN(x + attn)
        ln_kernel<<<M, 256, 0, stream>>>(xbuf, proj,
                                         ln1w + (size_t)l * DD, ln1b + (size_t)l * DD, xb16);

        // 5. h = relu(x @ w1^T + b1) -> bf16 (clobbers q/k/v aliases; attn done)
        cvt_bf16<<<FFD * DD / 1024, 256, 0, stream>>>(w1l, wS);
        gemm_bf16<<<dim3(FFD / 128, M / 128), 256, 0, stream>>>(
            xb16, wS, b1l, nullptr, hb16, nullptr, nullptr, nullptr, nullptr, M, FFD, DD, 1);

        // 6. mlp = h @ w2^T + b2 -> proj f32
        cvt_bf16<<<DD * FFD / 1024, 256, 0, stream>>>(w2l, wS);
        gemm_bf16<<<dim3(DD / 128, M / 128), 256, 0, stream>>>(
            hb16, wS, b2l, proj, nullptr, nullptr, nullptr, nullptr, nullptr, M, DD, FFD, 0);

        // 7. x = LN(x + mlp)
        ln_kernel<<<M, 256, 0, stream>>>(xbuf, proj,
                                         ln2w + (size_t)l * DD, ln2b + (size_t)l * DD, xb16);
    }

    hipMemcpyAsync(out_x, xbuf, (size_t)BSD * sizeof(float),
                   hipMemcpyDeviceToDevice, stream);
}

// Round 4
// 1621.193 us; speedup vs baseline: 5.7653x; 1.1981x over previous
//
#include <hip/hip_runtime.h>
#include <cstdint>
#include <cstddef>
#include <math.h>

// Problem dims (fixed)
#define LL  8
#define BB  2
#define SS  1024
#define DD  1024
#define HH  16
#define HD  64
#define FFD 4096
#define BSD (BB*SS*DD)   // 2,097,152

typedef __attribute__((ext_vector_type(4))) float f32x4;
typedef __attribute__((ext_vector_type(8))) short bf16x8;
typedef __attribute__((ext_vector_type(4))) short bf16x4;

__device__ __forceinline__ unsigned short f2bf(float f) {
    unsigned u = __float_as_uint(f);
    unsigned r = (u + 0x7fffu + ((u >> 16) & 1u)) >> 16;   // RTN-even
    return (unsigned short)r;
}

#define GLD16(gsrc, ldst) \
    __builtin_amdgcn_global_load_lds((const __attribute__((address_space(1))) void*)(gsrc), \
                                     (__attribute__((address_space(3))) void*)(ldst), 16, 0, 0)

// ---------------------------------------------------------------------------
// f32 -> bf16 elementwise convert (4 elems/thread)
// ---------------------------------------------------------------------------
__global__ __launch_bounds__(256)
void cvt_bf16(const float* __restrict__ in, unsigned short* __restrict__ out)
{
    size_t i = (size_t)blockIdx.x * 256 + threadIdx.x;
    float4 v = *(const float4*)(in + i * 4);
    ushort4 o;
    o.x = f2bf(v.x); o.y = f2bf(v.y); o.z = f2bf(v.z); o.w = f2bf(v.w);
    *(ushort4*)(out + i * 4) = o;
}

// ---------------------------------------------------------------------------
// bf16 MFMA GEMM: C[M,N] = A[M,K_chunk] * W[N,K_chunk]^T (+ bias)
// 128x128 tile, BK=32, 512 threads = 8 waves (2Mx4N), each wave 64x32 out
// (4x2 frags of 16x16x32). Split-K via blockIdx.z (klen per z).
// mode 1: relu -> bf16 Cb (full K, bias)
// mode 2: QKV split (full K, bias): seg0 -> Cb(q bf16); seg1 -> Ck f32 + Kb16;
//         seg2 -> Cv f32 + Vb16
// mode 3: f32 partial -> C + z*M*N (no bias; LN fuses the combine)
// ---------------------------------------------------------------------------
__global__ __launch_bounds__(512)
void gemm_bf16(const unsigned short* __restrict__ A, const unsigned short* __restrict__ W,
               const float* __restrict__ bias,
               float* __restrict__ C, unsigned short* __restrict__ Cb,
               float* __restrict__ Ck, float* __restrict__ Cv,
               unsigned short* __restrict__ Kb16, unsigned short* __restrict__ Vb16,
               int M, int N, int klen, int mode)
{
    __shared__ unsigned short As[128 * 32];
    __shared__ unsigned short Ws[128 * 32];

    const int tid  = threadIdx.x;
    const int m0   = blockIdx.y * 128;
    const int n0   = blockIdx.x * 128;
    const int kbase= blockIdx.z * klen;
    const int lane = tid & 63;
    const int w    = tid >> 6;          // 0..7
    const int wr   = w >> 2;            // 0..1 (M)
    const int wc   = w & 3;             // 0..3 (N)
    const int lr   = lane & 15;
    const int kq   = lane >> 4;

    const int K = (mode == 3) ? (klen * gridDim.z) : klen;   // row stride of A/W

    f32x4 acc[4][2];
    #pragma unroll
    for (int i = 0; i < 4; ++i)
        #pragma unroll
        for (int j = 0; j < 2; ++j) {
            f32x4 z = {0.f, 0.f, 0.f, 0.f};
            acc[i][j] = z;
        }

    const int srow = tid >> 2;          // 0..127
    const int skp  = tid & 3;           // 16B chunk
    for (int kt = 0; kt < klen; kt += 32) {
        if (kt) __syncthreads();
        GLD16(A + (size_t)(m0 + srow) * K + kbase + kt + skp * 8, As + tid * 8);
        GLD16(W + (size_t)(n0 + srow) * K + kbase + kt + skp * 8, Ws + tid * 8);
        __syncthreads();

        bf16x8 a[4], b[2];
        #pragma unroll
        for (int fi = 0; fi < 4; ++fi)
            a[fi] = *(const bf16x8*)(As + (wr * 64 + fi * 16 + lr) * 32 + kq * 8);
        #pragma unroll
        for (int fj = 0; fj < 2; ++fj)
            b[fj] = *(const bf16x8*)(Ws + (wc * 32 + fj * 16 + lr) * 32 + kq * 8);
        #pragma unroll
        for (int fi = 0; fi < 4; ++fi)
            #pragma unroll
            for (int fj = 0; fj < 2; ++fj)
                acc[fi][fj] = __builtin_amdgcn_mfma_f32_16x16x32_bf16(
                    a[fi], b[fj], acc[fi][fj], 0, 0, 0);
    }

    // Epilogue. C/D layout: col = lane&15, row = (lane>>4)*4 + reg
    const int seg = n0 >> 10;
    float* Cp = (mode == 3) ? (C + (size_t)blockIdx.z * M * N) : C;
    #pragma unroll
    for (int fj = 0; fj < 2; ++fj) {
        const int cl = wc * 32 + fj * 16 + lr;          // 0..127
        const float bv = (mode == 3) ? 0.f : bias[n0 + cl];
        #pragma unroll
        for (int fi = 0; fi < 4; ++fi) {
            #pragma unroll
            for (int r = 0; r < 4; ++r) {
                const int row = m0 + wr * 64 + fi * 16 + kq * 4 + r;
                const float val = acc[fi][fj][r] + bv;
                if (mode == 2) {
                    const int col = (n0 & 1023) + cl;
                    float* dstf = (seg == 1) ? Ck : ((seg == 2) ? Cv : nullptr);
                    unsigned short* dstb = (seg == 0) ? Cb : ((seg == 1) ? Kb16 : Vb16);
                    if (dstf) dstf[(size_t)row * DD + col] = val;
                    dstb[(size_t)row * DD + col] = f2bf(val);
                } else if (mode == 1) {
                    Cb[(size_t)row * N + n0 + cl] = f2bf(fmaxf(val, 0.f));
                } else {
                    Cp[(size_t)row * N + n0 + cl] = val;
                }
            }
        }
    }
}

// ---------------------------------------------------------------------------
// MFMA causal flash attention (unchanged from R3). Block = (64 q, h, b),
// 256 thr = 4 waves; K/Vt/P bf16 in LDS, stride-68 rows.
// ---------------------------------------------------------------------------
__global__ __launch_bounds__(256)
void attn_mfma(const unsigned short* __restrict__ Qb, const unsigned short* __restrict__ Kb,
               const unsigned short* __restrict__ Vb, unsigned short* __restrict__ ctxb)
{
    const int qt = blockIdx.x;
    const int h  = blockIdx.y;
    const int b  = blockIdx.z;
    const int tid  = threadIdx.x;
    const int lane = tid & 63;
    const int w    = tid >> 6;
    const int lr   = lane & 15;
    const int hi   = lane >> 4;

    __shared__ unsigned short smem[(64 + 64 + 4 * 16) * 68];
    unsigned short* Ks = smem;
    unsigned short* Vt = smem + 64 * 68;
    unsigned short* Pl = smem + 128 * 68 + w * 16 * 68;

    bf16x8 qa[2];
    {
        const unsigned short* qp =
            Qb + ((size_t)(b * SS + qt * 64 + w * 16 + lr)) * DD + h * HD;
        qa[0] = *(const bf16x8*)(qp + hi * 8);
        qa[1] = *(const bf16x8*)(qp + 32 + hi * 8);
    }

    f32x4 accO[4];
    #pragma unroll
    for (int t = 0; t < 4; ++t) { f32x4 z = {0.f,0.f,0.f,0.f}; accO[t] = z; }
    float m_run[4], l_run[4];
    #pragma unroll
    for (int r = 0; r < 4; ++r) { m_run[r] = -INFINITY; l_run[r] = 0.f; }

    for (int c = 0; c <= qt; ++c) {
        __syncthreads();
        const unsigned short* kb = Kb + ((size_t)(b * SS + c * 64)) * DD + h * HD;
        const unsigned short* vb = Vb + ((size_t)(b * SS + c * 64)) * DD + h * HD;
        #pragma unroll
        for (int i = 0; i < 2; ++i) {
            int e  = tid + i * 256;
            int r  = e >> 3, ch = e & 7;
            bf16x8 kv = *(const bf16x8*)(kb + (size_t)r * DD + ch * 8);
            *(bf16x4*)(Ks + r * 68 + ch * 8)     = __builtin_shufflevector(kv, kv, 0,1,2,3);
            *(bf16x4*)(Ks + r * 68 + ch * 8 + 4) = __builtin_shufflevector(kv, kv, 4,5,6,7);
            int k  = e & 63, d0 = (e >> 6) * 8;
            bf16x8 vv = *(const bf16x8*)(vb + (size_t)k * DD + d0);
            #pragma unroll
            for (int j = 0; j < 8; ++j)
                Vt[(d0 + j) * 68 + k] = (unsigned short)vv[j];
        }
        __syncthreads();

        f32x4 sa[4];
        #pragma unroll
        for (int t = 0; t < 4; ++t) { f32x4 z = {0.f,0.f,0.f,0.f}; sa[t] = z; }
        #pragma unroll
        for (int t = 0; t < 4; ++t) {
            #pragma unroll
            for (int s = 0; s < 2; ++s) {
                const unsigned short* bp = Ks + (t * 16 + lr) * 68 + s * 32 + hi * 8;
                bf16x4 b0 = *(const bf16x4*)bp;
                bf16x4 b1 = *(const bf16x4*)(bp + 4);
                bf16x8 bb = __builtin_shufflevector(b0, b1, 0,1,2,3,4,5,6,7);
                sa[t] = __builtin_amdgcn_mfma_f32_16x16x32_bf16(qa[s], bb, sa[t], 0, 0, 0);
            }
        }
        #pragma unroll
        for (int t = 0; t < 4; ++t)
            #pragma unroll
            for (int r = 0; r < 4; ++r)
                sa[t][r] *= 0.125f;
        if (c == qt) {
            const int qg = w * 16 + hi * 4;
            #pragma unroll
            for (int t = 0; t < 4; ++t)
                #pragma unroll
                for (int r = 0; r < 4; ++r)
                    if (t * 16 + lr > qg + r) sa[t][r] = -1e30f;
        }
        #pragma unroll
        for (int r = 0; r < 4; ++r) {
            float mx = fmaxf(fmaxf(sa[0][r], sa[1][r]), fmaxf(sa[2][r], sa[3][r]));
            mx = fmaxf(mx, __shfl_xor(mx, 1));
            mx = fmaxf(mx, __shfl_xor(mx, 2));
            mx = fmaxf(mx, __shfl_xor(mx, 4));
            mx = fmaxf(mx, __shfl_xor(mx, 8));
            const float mn = fmaxf(m_run[r], mx);
            float sum = 0.f;
            #pragma unroll
            for (int t = 0; t < 4; ++t) {
                float p = __expf(sa[t][r] - mn);
                sa[t][r] = p;
                sum += p;
            }
            sum += __shfl_xor(sum, 1);
            sum += __shfl_xor(sum, 2);
            sum += __shfl_xor(sum, 4);
            sum += __shfl_xor(sum, 8);
            const float sc = __expf(m_run[r] - mn);
            l_run[r] = l_run[r] * sc + sum;
            m_run[r] = mn;
            #pragma unroll
            for (int t = 0; t < 4; ++t) accO[t][r] *= sc;
        }
        #pragma unroll
        for (int t = 0; t < 4; ++t)
            #pragma unroll
            for (int r = 0; r < 4; ++r)
                Pl[(hi * 4 + r) * 68 + t * 16 + lr] = f2bf(sa[t][r]);

        #pragma unroll
        for (int s = 0; s < 2; ++s) {
            const unsigned short* ap = Pl + lr * 68 + s * 32 + hi * 8;
            bf16x4 a0 = *(const bf16x4*)ap;
            bf16x4 a1 = *(const bf16x4*)(ap + 4);
            bf16x8 aa = __builtin_shufflevector(a0, a1, 0,1,2,3,4,5,6,7);
            #pragma unroll
            for (int t = 0; t < 4; ++t) {
                const unsigned short* bp = Vt + (t * 16 + lr) * 68 + s * 32 + hi * 8;
                bf16x4 b0 = *(const bf16x4*)bp;
                bf16x4 b1 = *(const bf16x4*)(bp + 4);
                bf16x8 bb = __builtin_shufflevector(b0, b1, 0,1,2,3,4,5,6,7);
                accO[t] = __builtin_amdgcn_mfma_f32_16x16x32_bf16(aa, bb, accO[t], 0, 0, 0);
            }
        }
    }

    float inv[4];
    #pragma unroll
    for (int r = 0; r < 4; ++r) inv[r] = 1.f / l_run[r];

    __syncthreads();
    float* Of = (float*)smem;
    #pragma unroll
    for (int t = 0; t < 4; ++t)
        #pragma unroll
        for (int r = 0; r < 4; ++r)
            Of[(w * 16 + hi * 4 + r) * 68 + t * 16 + lr] = accO[t][r] * inv[r];
    __syncthreads();
    #pragma unroll
    for (int i = 0; i < 2; ++i) {
        int e = tid + i * 256;
        int r = e >> 3, ch = e & 7;
        const float* src = Of + r * 68 + ch * 8;
        float4 v0 = *(const float4*)(src);
        float4 v1 = *(const float4*)(src + 4);
        bf16x8 o;
        o[0] = (short)f2bf(v0.x); o[1] = (short)f2bf(v0.y);
        o[2] = (short)f2bf(v0.z); o[3] = (short)f2bf(v0.w);
        o[4] = (short)f2bf(v1.x); o[5] = (short)f2bf(v1.y);
        o[6] = (short)f2bf(v1.z); o[7] = (short)f2bf(v1.w);
        *(bf16x8*)(ctxb + ((size_t)(b * SS + qt * 64 + r)) * DD + h * HD + ch * 8) = o;
    }
}

// ---------------------------------------------------------------------------
// x = LayerNorm(x + P0+P1+P2+P3 + bias) * w + b ; writes bf16 copy too.
// Fuses the split-K combine (P = 4 partials, stride PS) and the GEMM bias.
// ---------------------------------------------------------------------------
__global__ __launch_bounds__(256)
void ln_kernel(float* __restrict__ x, const float* __restrict__ P,
               const float* __restrict__ bias,
               const float* __restrict__ w, const float* __restrict__ b,
               unsigned short* __restrict__ xb)
{
    const size_t PS = (size_t)BB * SS * DD;   // partial stride
    const int row = blockIdx.x;
    const int t   = threadIdx.x;
    float* xr = x + (size_t)row * DD;
    unsigned short* xbr = xb + (size_t)row * DD;

    float z[4];
    float s = 0.f, ss = 0.f;
    #pragma unroll
    for (int i = 0; i < 4; ++i) {
        int d = t + i * 256;
        size_t idx = (size_t)row * DD + d;
        float v = xr[d] + bias[d] + P[idx] + P[idx + PS] + P[idx + 2 * PS] + P[idx + 3 * PS];
        z[i] = v;
        s  += v;
        ss += v * v;
    }
    #pragma unroll
    for (int off = 32; off; off >>= 1) {
        s  += __shfl_down(s, off);
        ss += __shfl_down(ss, off);
    }
    __shared__ float sbuf[4], ssbuf[4];
    const int wave = t >> 6, lane = t & 63;
    if (lane == 0) { sbuf[wave] = s; ssbuf[wave] = ss; }
    __syncthreads();
    if (t == 0) {
        float S = 0.f, SSum = 0.f;
        #pragma unroll
        for (int i = 0; i < 4; ++i) { S += sbuf[i]; SSum += ssbuf[i]; }
        float mean = S * (1.f / 1024.f);
        float var  = SSum * (1.f / 1024.f) - mean * mean;
        sbuf[0]  = mean;
        ssbuf[0] = rsqrtf(var + 1e-5f);
    }
    __syncthreads();
    const float mean = sbuf[0], rstd = ssbuf[0];
    #pragma unroll
    for (int i = 0; i < 4; ++i) {
        int d = t + i * 256;
        float v = (z[i] - mean) * rstd * w[d] + b[d];
        xr[d]  = v;
        xbr[d] = f2bf(v);
    }
}

// ---------------------------------------------------------------------------
extern "C" void kernel_launch(void* const* d_in, const int* in_sizes, int n_in,
                              void* d_out, int out_size, void* d_ws, size_t ws_size,
                              hipStream_t stream)
{
    const float* x_in  = (const float*)d_in[0];
    const float* qkv_w = (const float*)d_in[2];
    const float* qkv_b = (const float*)d_in[3];
    const float* out_w = (const float*)d_in[4];
    const float* out_b = (const float*)d_in[5];
    const float* w1    = (const float*)d_in[6];
    const float* b1    = (const float*)d_in[7];
    const float* w2    = (const float*)d_in[8];
    const float* b2    = (const float*)d_in[9];
    const float* ln1w  = (const float*)d_in[10];
    const float* ln1b  = (const float*)d_in[11];
    const float* ln2w  = (const float*)d_in[12];
    const float* ln2b  = (const float*)d_in[13];

    float* out_x = (float*)d_out;                    // [B,S,D]
    float* out_k = out_x + (size_t)BSD;              // [L,B,S,D]
    float* out_v = out_k + (size_t)LL * BSD;         // [L,B,S,D]

    const size_t MEG = 1024 * 1024;
    float* ws = (float*)d_ws;
    float*          xbuf = ws;                                // 2M f32
    float*          part = ws + 2 * MEG;                      // 4 x 2M f32 partials
    unsigned short* xb16 = (unsigned short*)(ws + 10 * MEG);  // 2M bf16
    unsigned short* ctxb = (unsigned short*)(ws + 11 * MEG);  // 2M bf16
    unsigned short* hb16 = (unsigned short*)(ws + 12 * MEG);  // 8M bf16
    unsigned short* qb16 = hb16;                              // aliases (disjoint lifetime)
    unsigned short* kb16 = hb16 + 2 * MEG;
    unsigned short* vb16 = hb16 + 4 * MEG;
    unsigned short* wAll = (unsigned short*)(ws + 16 * MEG);  // 96M bf16 weights

    // bf16 weight regions (grouped by tensor, all layers)
    unsigned short* qkvW = wAll;                     // 24M
    unsigned short* outW = wAll + 24 * MEG;          //  8M
    unsigned short* w1W  = wAll + 32 * MEG;          // 32M
    unsigned short* w2W  = wAll + 64 * MEG;          // 32M

    // Convert all weights once per call (4 launches)
    cvt_bf16<<<24 * MEG / 1024, 256, 0, stream>>>(qkv_w, qkvW);
    cvt_bf16<<< 8 * MEG / 1024, 256, 0, stream>>>(out_w, outW);
    cvt_bf16<<<32 * MEG / 1024, 256, 0, stream>>>(w1,    w1W);
    cvt_bf16<<<32 * MEG / 1024, 256, 0, stream>>>(w2,    w2W);

    hipMemcpyAsync(xbuf, x_in, (size_t)BSD * sizeof(float),
                   hipMemcpyDeviceToDevice, stream);
    cvt_bf16<<<BSD / 1024, 256, 0, stream>>>(x_in, xb16);

    const int M = BB * SS;   // 2048

    for (int l = 0; l < LL; ++l) {
        const float* qb  = qkv_b + (size_t)l * 3 * DD;
        const float* ob  = out_b + (size_t)l * DD;
        const float* b1l = b1    + (size_t)l * FFD;
        const float* b2l = b2    + (size_t)l * DD;
        const unsigned short* qwl = qkvW + (size_t)l * 3 * DD * DD;
        const unsigned short* owl = outW + (size_t)l * DD * DD;
        const unsigned short* w1l = w1W  + (size_t)l * FFD * DD;
        const unsigned short* w2l = w2W  + (size_t)l * DD * FFD;
        float* kc = out_k + (size_t)l * BSD;
        float* vc = out_v + (size_t)l * BSD;

        // 1. QKV projection (full K): q/k/v bf16 + f32 caches
        gemm_bf16<<<dim3(3 * DD / 128, M / 128, 1), 512, 0, stream>>>(
            xb16, qwl, qb, nullptr, qb16, kc, vc, kb16, vb16, M, 3 * DD, DD, 2);

        // 2. MFMA causal attention -> bf16 ctx
        attn_mfma<<<dim3(SS / 64, HH, BB), 256, 0, stream>>>(qb16, kb16, vb16, ctxb);

        // 3. output projection, split-K x4 -> f32 partials
        gemm_bf16<<<dim3(DD / 128, M / 128, 4), 512, 0, stream>>>(
            ctxb, owl, nullptr, part, nullptr, nullptr, nullptr, nullptr, nullptr,
            M, DD, DD / 4, 3);

        // 4. x = LN(x + Σpart + ob)
        ln_kernel<<<M, 256, 0, stream>>>(xbuf, part, ob,
                                         ln1w + (size_t)l * DD, ln1b + (size_t)l * DD, xb16);

        // 5. h = relu(x @ w1^T + b1) -> bf16 (clobbers q/k/v aliases; attn done)
        gemm_bf16<<<dim3(FFD / 128, M / 128, 1), 512, 0, stream>>>(
            xb16, w1l, b1l, nullptr, hb16, nullptr, nullptr, nullptr, nullptr,
            M, FFD, DD, 1);

        // 6. mlp = h @ w2^T, split-K x4 -> f32 partials
        gemm_bf16<<<dim3(DD / 128, M / 128, 4), 512, 0, stream>>>(
            hb16, w2l, nullptr, part, nullptr, nullptr, nullptr, nullptr, nullptr,
            M, DD, FFD / 4, 3);

        // 7. x = LN(x + Σpart + b2)
        ln_kernel<<<M, 256, 0, stream>>>(xbuf, part, b2l,
                                         ln2w + (size_t)l * DD, ln2b + (size_t)l * DD, xb16);
    }

    hipMemcpyAsync(out_x, xbuf, (size_t)BSD * sizeof(float),
                   hipMemcpyDeviceToDevice, stream);
}

// Round 7
// 1354.419 us; speedup vs baseline: 6.9008x; 1.1970x over previous
//
#include <hip/hip_runtime.h>
#include <cstdint>
#include <cstddef>
#include <math.h>

// Problem dims (fixed)
#define LL  8
#define BB  2
#define SS  1024
#define DD  1024
#define HH  16
#define HD  64
#define FFD 4096
#define BSD (BB*SS*DD)   // 2,097,152

typedef __attribute__((ext_vector_type(4))) float f32x4;
typedef __attribute__((ext_vector_type(8))) short bf16x8;
typedef __attribute__((ext_vector_type(4))) short bf16x4;

__device__ __forceinline__ unsigned short f2bf(float f) {
    unsigned u = __float_as_uint(f);
    unsigned r = (u + 0x7fffu + ((u >> 16) & 1u)) >> 16;   // RTN-even
    return (unsigned short)r;
}

#define GLD16(gsrc, ldst) \
    __builtin_amdgcn_global_load_lds((const __attribute__((address_space(1))) void*)(gsrc), \
                                     (__attribute__((address_space(3))) void*)(ldst), 16, 0, 0)

// ---------------------------------------------------------------------------
// f32 -> bf16 elementwise convert (4 elems/thread)
// ---------------------------------------------------------------------------
__global__ __launch_bounds__(256)
void cvt_bf16(const float* __restrict__ in, unsigned short* __restrict__ out)
{
    size_t i = (size_t)blockIdx.x * 256 + threadIdx.x;
    float4 v = *(const float4*)(in + i * 4);
    ushort4 o;
    o.x = f2bf(v.x); o.y = f2bf(v.y); o.z = f2bf(v.z); o.w = f2bf(v.w);
    *(ushort4*)(out + i * 4) = o;
}

// ---------------------------------------------------------------------------
// bf16 MFMA GEMM, double-buffered BK=64 with counted (non-draining) vmcnt.
// C[M,N] = A[M,Kchunk] * W[N,Kchunk]^T (+bias). 128x128 tile, 512 thr =
// 8 waves (2Mx4N), wave = 64x32 out (4x2 frags 16x16x32), 2 K-tiles in LDS
// (64 KB). T2 XOR swizzle: linear LDS dest (gload_lds) + pre-swizzled global
// source column + same involution on ds_read (rule 21 both-sides).
// vmcnt ledger: prologue 8 in flight; steady iter waits vmcnt(4) (tile t
// landed, t+1 in flight); FINAL iter waits vmcnt(0) (epilogue drain — the
// R5 bug was omitting this).
// mode 1: relu -> bf16 Cb      mode 2: QKV split (q bf16 / k,v f32+bf16)
// mode 3: f32 partial -> C + z*M*N (split-K; LN fuses combine)
// ---------------------------------------------------------------------------
__global__ __launch_bounds__(512)
void gemm_bf16(const unsigned short* __restrict__ A, const unsigned short* __restrict__ W,
               const float* __restrict__ bias,
               float* __restrict__ C, unsigned short* __restrict__ Cb,
               float* __restrict__ Ck, float* __restrict__ Cv,
               unsigned short* __restrict__ Kb16, unsigned short* __restrict__ Vb16,
               int M, int N, int klen, int mode)
{
    __shared__ unsigned short lds[2][2 * 128 * 64];   // [dbuf][A(8192) | W(8192)]

    const int tid  = threadIdx.x;
    const int m0   = blockIdx.y * 128;
    const int n0   = blockIdx.x * 128;
    const int kbase= blockIdx.z * klen;
    const int lane = tid & 63;
    const int w    = tid >> 6;          // 0..7
    const int wr   = w >> 2;            // 0..1 (M half)
    const int wc   = w & 3;             // 0..3 (N quarter)
    const int lr   = lane & 15;
    const int kq   = lane >> 4;

    const int K = (mode == 3) ? (klen * gridDim.z) : klen;   // row stride of A/W
    const int T = klen >> 6;                                  // # BK=64 tiles

    // Staging geometry: chunk c = tid + i*512 (i=0,1); row = c>>3, physical
    // chunk pc = c&7, logical (global) col chunk lc = pc ^ (row&7).
    const int srow0 = tid >> 3;            // i=0: rows 0..63
    const int spc0  = tid & 7;
    const int slc0  = spc0 ^ (srow0 & 7);
    const int srow1 = (tid + 512) >> 3;    // i=1: rows 64..127
    const int spc1  = (tid + 512) & 7;
    const int slc1  = spc1 ^ (srow1 & 7);

    #define STAGE_TILE(ti, dst)                                                   \
        do {                                                                      \
            const int kc = kbase + (ti) * 64;                                     \
            GLD16(A + (size_t)(m0 + srow0) * K + kc + slc0 * 8, (dst) + tid * 8); \
            GLD16(A + (size_t)(m0 + srow1) * K + kc + slc1 * 8, (dst) + 4096 + tid * 8); \
            GLD16(W + (size_t)(n0 + srow0) * K + kc + slc0 * 8, (dst) + 8192 + tid * 8); \
            GLD16(W + (size_t)(n0 + srow1) * K + kc + slc1 * 8, (dst) + 12288 + tid * 8); \
        } while (0)

    f32x4 acc[4][2];
    #pragma unroll
    for (int i = 0; i < 4; ++i)
        #pragma unroll
        for (int j = 0; j < 2; ++j) {
            f32x4 z = {0.f, 0.f, 0.f, 0.f};
            acc[i][j] = z;
        }

    // Prologue: stage tiles 0 and 1 (8 loads outstanding)
    STAGE_TILE(0, lds[0]);
    STAGE_TILE(1, lds[1]);

    for (int t = 0; t < T; ++t) {
        unsigned short* cb = lds[t & 1];

        if (t == T - 1) {
            // final tile: nothing else in flight behind it -> full drain
            asm volatile("s_waitcnt vmcnt(0)\n\ts_barrier" ::: "memory");
        } else {
            // tile t landed (tile t+1's 4 loads may remain in flight)
            asm volatile("s_waitcnt vmcnt(4)\n\ts_barrier" ::: "memory");
        }

        // ds_read fragments (swizzled column chunks)
        bf16x8 a[4][2], b[2][2];
        #pragma unroll
        for (int mf = 0; mf < 4; ++mf) {
            const int r = wr * 64 + mf * 16 + lr;
            #pragma unroll
            for (int kk = 0; kk < 2; ++kk) {
                const int pc = (kk * 4 + kq) ^ (r & 7);
                a[mf][kk] = *(const bf16x8*)(cb + r * 64 + pc * 8);
            }
        }
        #pragma unroll
        for (int nf = 0; nf < 2; ++nf) {
            const int r = wc * 32 + nf * 16 + lr;
            #pragma unroll
            for (int kk = 0; kk < 2; ++kk) {
                const int pc = (kk * 4 + kq) ^ (r & 7);
                b[nf][kk] = *(const bf16x8*)(cb + 8192 + r * 64 + pc * 8);
            }
        }

        // all waves' reads of this buffer complete -> safe to overwrite
        asm volatile("s_waitcnt lgkmcnt(0)\n\ts_barrier" ::: "memory");

        if (t + 2 < T) STAGE_TILE(t + 2, cb);
        __builtin_amdgcn_sched_barrier(0);   // keep stage issue before MFMA

        __builtin_amdgcn_s_setprio(1);
        #pragma unroll
        for (int kk = 0; kk < 2; ++kk)
            #pragma unroll
            for (int mf = 0; mf < 4; ++mf)
                #pragma unroll
                for (int nf = 0; nf < 2; ++nf)
                    acc[mf][nf] = __builtin_amdgcn_mfma_f32_16x16x32_bf16(
                        a[mf][kk], b[nf][kk], acc[mf][nf], 0, 0, 0);
        __builtin_amdgcn_s_setprio(0);
    }
    #undef STAGE_TILE

    // Epilogue. C/D layout: col = lane&15, row = (lane>>4)*4 + reg
    const int seg = n0 >> 10;
    float* Cp = (mode == 3) ? (C + (size_t)blockIdx.z * M * N) : C;
    #pragma unroll
    for (int nf = 0; nf < 2; ++nf) {
        const int cl = wc * 32 + nf * 16 + lr;          // 0..127
        const float bv = (mode == 3) ? 0.f : bias[n0 + cl];
        #pragma unroll
        for (int mf = 0; mf < 4; ++mf) {
            #pragma unroll
            for (int r = 0; r < 4; ++r) {
                const int row = m0 + wr * 64 + mf * 16 + kq * 4 + r;
                const float val = acc[mf][nf][r] + bv;
                if (mode == 2) {
                    const int col = (n0 & 1023) + cl;
                    float* dstf = (seg == 1) ? Ck : ((seg == 2) ? Cv : nullptr);
                    unsigned short* dstb = (seg == 0) ? Cb : ((seg == 1) ? Kb16 : Vb16);
                    if (dstf) dstf[(size_t)row * DD + col] = val;
                    dstb[(size_t)row * DD + col] = f2bf(val);
                } else if (mode == 1) {
                    Cb[(size_t)row * N + n0 + cl] = f2bf(fmaxf(val, 0.f));
                } else {
                    Cp[(size_t)row * N + n0 + cl] = val;
                }
            }
        }
    }
}

// ---------------------------------------------------------------------------
// MFMA causal flash attention (unchanged). Block = (64 q, h, b),
// 256 thr = 4 waves; K/Vt/P bf16 in LDS, stride-68 rows.
// ---------------------------------------------------------------------------
__global__ __launch_bounds__(256)
void attn_mfma(const unsigned short* __restrict__ Qb, const unsigned short* __restrict__ Kb,
               const unsigned short* __restrict__ Vb, unsigned short* __restrict__ ctxb)
{
    const int qt = blockIdx.x;
    const int h  = blockIdx.y;
    const int b  = blockIdx.z;
    const int tid  = threadIdx.x;
    const int lane = tid & 63;
    const int w    = tid >> 6;
    const int lr   = lane & 15;
    const int hi   = lane >> 4;

    __shared__ unsigned short smem[(64 + 64 + 4 * 16) * 68];
    unsigned short* Ks = smem;
    unsigned short* Vt = smem + 64 * 68;
    unsigned short* Pl = smem + 128 * 68 + w * 16 * 68;

    bf16x8 qa[2];
    {
        const unsigned short* qp =
            Qb + ((size_t)(b * SS + qt * 64 + w * 16 + lr)) * DD + h * HD;
        qa[0] = *(const bf16x8*)(qp + hi * 8);
        qa[1] = *(const bf16x8*)(qp + 32 + hi * 8);
    }

    f32x4 accO[4];
    #pragma unroll
    for (int t = 0; t < 4; ++t) { f32x4 z = {0.f,0.f,0.f,0.f}; accO[t] = z; }
    float m_run[4], l_run[4];
    #pragma unroll
    for (int r = 0; r < 4; ++r) { m_run[r] = -INFINITY; l_run[r] = 0.f; }

    for (int c = 0; c <= qt; ++c) {
        __syncthreads();
        const unsigned short* kb = Kb + ((size_t)(b * SS + c * 64)) * DD + h * HD;
        const unsigned short* vb = Vb + ((size_t)(b * SS + c * 64)) * DD + h * HD;
        #pragma unroll
        for (int i = 0; i < 2; ++i) {
            int e  = tid + i * 256;
            int r  = e >> 3, ch = e & 7;
            bf16x8 kv = *(const bf16x8*)(kb + (size_t)r * DD + ch * 8);
            *(bf16x4*)(Ks + r * 68 + ch * 8)     = __builtin_shufflevector(kv, kv, 0,1,2,3);
            *(bf16x4*)(Ks + r * 68 + ch * 8 + 4) = __builtin_shufflevector(kv, kv, 4,5,6,7);
            int k  = e & 63, d0 = (e >> 6) * 8;
            bf16x8 vv = *(const bf16x8*)(vb + (size_t)k * DD + d0);
            #pragma unroll
            for (int j = 0; j < 8; ++j)
                Vt[(d0 + j) * 68 + k] = (unsigned short)vv[j];
        }
        __syncthreads();

        f32x4 sa[4];
        #pragma unroll
        for (int t = 0; t < 4; ++t) { f32x4 z = {0.f,0.f,0.f,0.f}; sa[t] = z; }
        #pragma unroll
        for (int t = 0; t < 4; ++t) {
            #pragma unroll
            for (int s = 0; s < 2; ++s) {
                const unsigned short* bp = Ks + (t * 16 + lr) * 68 + s * 32 + hi * 8;
                bf16x4 b0 = *(const bf16x4*)bp;
                bf16x4 b1 = *(const bf16x4*)(bp + 4);
                bf16x8 bb = __builtin_shufflevector(b0, b1, 0,1,2,3,4,5,6,7);
                sa[t] = __builtin_amdgcn_mfma_f32_16x16x32_bf16(qa[s], bb, sa[t], 0, 0, 0);
            }
        }
        #pragma unroll
        for (int t = 0; t < 4; ++t)
            #pragma unroll
            for (int r = 0; r < 4; ++r)
                sa[t][r] *= 0.125f;
        if (c == qt) {
            const int qg = w * 16 + hi * 4;
            #pragma unroll
            for (int t = 0; t < 4; ++t)
                #pragma unroll
                for (int r = 0; r < 4; ++r)
                    if (t * 16 + lr > qg + r) sa[t][r] = -1e30f;
        }
        #pragma unroll
        for (int r = 0; r < 4; ++r) {
            float mx = fmaxf(fmaxf(sa[0][r], sa[1][r]), fmaxf(sa[2][r], sa[3][r]));
            mx = fmaxf(mx, __shfl_xor(mx, 1));
            mx = fmaxf(mx, __shfl_xor(mx, 2));
            mx = fmaxf(mx, __shfl_xor(mx, 4));
            mx = fmaxf(mx, __shfl_xor(mx, 8));
            const float mn = fmaxf(m_run[r], mx);
            float sum = 0.f;
            #pragma unroll
            for (int t = 0; t < 4; ++t) {
                float p = __expf(sa[t][r] - mn);
                sa[t][r] = p;
                sum += p;
            }
            sum += __shfl_xor(sum, 1);
            sum += __shfl_xor(sum, 2);
            sum += __shfl_xor(sum, 4);
            sum += __shfl_xor(sum, 8);
            const float sc = __expf(m_run[r] - mn);
            l_run[r] = l_run[r] * sc + sum;
            m_run[r] = mn;
            #pragma unroll
            for (int t = 0; t < 4; ++t) accO[t][r] *= sc;
        }
        #pragma unroll
        for (int t = 0; t < 4; ++t)
            #pragma unroll
            for (int r = 0; r < 4; ++r)
                Pl[(hi * 4 + r) * 68 + t * 16 + lr] = f2bf(sa[t][r]);

        #pragma unroll
        for (int s = 0; s < 2; ++s) {
            const unsigned short* ap = Pl + lr * 68 + s * 32 + hi * 8;
            bf16x4 a0 = *(const bf16x4*)ap;
            bf16x4 a1 = *(const bf16x4*)(ap + 4);
            bf16x8 aa = __builtin_shufflevector(a0, a1, 0,1,2,3,4,5,6,7);
            #pragma unroll
            for (int t = 0; t < 4; ++t) {
                const unsigned short* bp = Vt + (t * 16 + lr) * 68 + s * 32 + hi * 8;
                bf16x4 b0 = *(const bf16x4*)bp;
                bf16x4 b1 = *(const bf16x4*)(bp + 4);
                bf16x8 bb = __builtin_shufflevector(b0, b1, 0,1,2,3,4,5,6,7);
                accO[t] = __builtin_amdgcn_mfma_f32_16x16x32_bf16(aa, bb, accO[t], 0, 0, 0);
            }
        }
    }

    float inv[4];
    #pragma unroll
    for (int r = 0; r < 4; ++r) inv[r] = 1.f / l_run[r];

    __syncthreads();
    float* Of = (float*)smem;
    #pragma unroll
    for (int t = 0; t < 4; ++t)
        #pragma unroll
        for (int r = 0; r < 4; ++r)
            Of[(w * 16 + hi * 4 + r) * 68 + t * 16 + lr] = accO[t][r] * inv[r];
    __syncthreads();
    #pragma unroll
    for (int i = 0; i < 2; ++i) {
        int e = tid + i * 256;
        int r = e >> 3, ch = e & 7;
        const float* src = Of + r * 68 + ch * 8;
        float4 v0 = *(const float4*)(src);
        float4 v1 = *(const float4*)(src + 4);
        bf16x8 o;
        o[0] = (short)f2bf(v0.x); o[1] = (short)f2bf(v0.y);
        o[2] = (short)f2bf(v0.z); o[3] = (short)f2bf(v0.w);
        o[4] = (short)f2bf(v1.x); o[5] = (short)f2bf(v1.y);
        o[6] = (short)f2bf(v1.z); o[7] = (short)f2bf(v1.w);
        *(bf16x8*)(ctxb + ((size_t)(b * SS + qt * 64 + r)) * DD + h * HD + ch * 8) = o;
    }
}

// ---------------------------------------------------------------------------
// x = LayerNorm(x + P0+P1+P2+P3 + bias) * w + b ; writes bf16 copy too.
// ---------------------------------------------------------------------------
__global__ __launch_bounds__(256)
void ln_kernel(float* __restrict__ x, const float* __restrict__ P,
               const float* __restrict__ bias,
               const float* __restrict__ w, const float* __restrict__ b,
               unsigned short* __restrict__ xb)
{
    const size_t PS = (size_t)BB * SS * DD;   // partial stride
    const int row = blockIdx.x;
    const int t   = threadIdx.x;
    float* xr = x + (size_t)row * DD;
    unsigned short* xbr = xb + (size_t)row * DD;

    float z[4];
    float s = 0.f, ss = 0.f;
    #pragma unroll
    for (int i = 0; i < 4; ++i) {
        int d = t + i * 256;
        size_t idx = (size_t)row * DD + d;
        float v = xr[d] + bias[d] + P[idx] + P[idx + PS] + P[idx + 2 * PS] + P[idx + 3 * PS];
        z[i] = v;
        s  += v;
        ss += v * v;
    }
    #pragma unroll
    for (int off = 32; off; off >>= 1) {
        s  += __shfl_down(s, off);
        ss += __shfl_down(ss, off);
    }
    __shared__ float sbuf[4], ssbuf[4];
    const int wave = t >> 6, lane = t & 63;
    if (lane == 0) { sbuf[wave] = s; ssbuf[wave] = ss; }
    __syncthreads();
    if (t == 0) {
        float S = 0.f, SSum = 0.f;
        #pragma unroll
        for (int i = 0; i < 4; ++i) { S += sbuf[i]; SSum += ssbuf[i]; }
        float mean = S * (1.f / 1024.f);
        float var  = SSum * (1.f / 1024.f) - mean * mean;
        sbuf[0]  = mean;
        ssbuf[0] = rsqrtf(var + 1e-5f);
    }
    __syncthreads();
    const float mean = sbuf[0], rstd = ssbuf[0];
    #pragma unroll
    for (int i = 0; i < 4; ++i) {
        int d = t + i * 256;
        float v = (z[i] - mean) * rstd * w[d] + b[d];
        xr[d]  = v;
        xbr[d] = f2bf(v);
    }
}

// ---------------------------------------------------------------------------
extern "C" void kernel_launch(void* const* d_in, const int* in_sizes, int n_in,
                              void* d_out, int out_size, void* d_ws, size_t ws_size,
                              hipStream_t stream)
{
    const float* x_in  = (const float*)d_in[0];
    const float* qkv_w = (const float*)d_in[2];
    const float* qkv_b = (const float*)d_in[3];
    const float* out_w = (const float*)d_in[4];
    const float* out_b = (const float*)d_in[5];
    const float* w1    = (const float*)d_in[6];
    const float* b1    = (const float*)d_in[7];
    const float* w2    = (const float*)d_in[8];
    const float* b2    = (const float*)d_in[9];
    const float* ln1w  = (const float*)d_in[10];
    const float* ln1b  = (const float*)d_in[11];
    const float* ln2w  = (const float*)d_in[12];
    const float* ln2b  = (const float*)d_in[13];

    float* out_x = (float*)d_out;                    // [B,S,D]
    float* out_k = out_x + (size_t)BSD;              // [L,B,S,D]
    float* out_v = out_k + (size_t)LL * BSD;         // [L,B,S,D]

    const size_t MEG = 1024 * 1024;
    float* ws = (float*)d_ws;
    float*          xbuf = ws;                                // 2M f32
    float*          part = ws + 2 * MEG;                      // 4 x 2M f32 partials
    unsigned short* xb16 = (unsigned short*)(ws + 10 * MEG);  // 2M bf16
    unsigned short* ctxb = (unsigned short*)(ws + 11 * MEG);  // 2M bf16
    unsigned short* hb16 = (unsigned short*)(ws + 12 * MEG);  // 8M bf16
    unsigned short* qb16 = hb16;                              // aliases (disjoint lifetime)
    unsigned short* kb16 = hb16 + 2 * MEG;
    unsigned short* vb16 = hb16 + 4 * MEG;
    unsigned short* wAll = (unsigned short*)(ws + 16 * MEG);  // 96M bf16 weights

    unsigned short* qkvW = wAll;                     // 24M
    unsigned short* outW = wAll + 24 * MEG;          //  8M
    unsigned short* w1W  = wAll + 32 * MEG;          // 32M
    unsigned short* w2W  = wAll + 64 * MEG;          // 32M

    // Convert all weights once per call (4 launches)
    cvt_bf16<<<24 * MEG / 1024, 256, 0, stream>>>(qkv_w, qkvW);
    cvt_bf16<<< 8 * MEG / 1024, 256, 0, stream>>>(out_w, outW);
    cvt_bf16<<<32 * MEG / 1024, 256, 0, stream>>>(w1,    w1W);
    cvt_bf16<<<32 * MEG / 1024, 256, 0, stream>>>(w2,    w2W);

    hipMemcpyAsync(xbuf, x_in, (size_t)BSD * sizeof(float),
                   hipMemcpyDeviceToDevice, stream);
    cvt_bf16<<<BSD / 1024, 256, 0, stream>>>(x_in, xb16);

    const int M = BB * SS;   // 2048

    for (int l = 0; l < LL; ++l) {
        const float* qb  = qkv_b + (size_t)l * 3 * DD;
        const float* ob  = out_b + (size_t)l * DD;
        const float* b1l = b1    + (size_t)l * FFD;
        const float* b2l = b2    + (size_t)l * DD;
        const unsigned short* qwl = qkvW + (size_t)l * 3 * DD * DD;
        const unsigned short* owl = outW + (size_t)l * DD * DD;
        const unsigned short* w1l = w1W  + (size_t)l * FFD * DD;
        const unsigned short* w2l = w2W  + (size_t)l * DD * FFD;
        float* kc = out_k + (size_t)l * BSD;
        float* vc = out_v + (size_t)l * BSD;

        // 1. QKV projection (full K): q/k/v bf16 + f32 caches
        gemm_bf16<<<dim3(3 * DD / 128, M / 128, 1), 512, 0, stream>>>(
            xb16, qwl, qb, nullptr, qb16, kc, vc, kb16, vb16, M, 3 * DD, DD, 2);

        // 2. MFMA causal attention -> bf16 ctx
        attn_mfma<<<dim3(SS / 64, HH, BB), 256, 0, stream>>>(qb16, kb16, vb16, ctxb);

        // 3. output projection, split-K x4 -> f32 partials
        gemm_bf16<<<dim3(DD / 128, M / 128, 4), 512, 0, stream>>>(
            ctxb, owl, nullptr, part, nullptr, nullptr, nullptr, nullptr, nullptr,
            M, DD, DD / 4, 3);

        // 4. x = LN(x + Σpart + ob)
        ln_kernel<<<M, 256, 0, stream>>>(xbuf, part, ob,
                                         ln1w + (size_t)l * DD, ln1b + (size_t)l * DD, xb16);

        // 5. h = relu(x @ w1^T + b1) -> bf16
        gemm_bf16<<<dim3(FFD / 128, M / 128, 1), 512, 0, stream>>>(
            xb16, w1l, b1l, nullptr, hb16, nullptr, nullptr, nullptr, nullptr,
            M, FFD, DD, 1);

        // 6. mlp = h @ w2^T, split-K x4 -> f32 partials
        gemm_bf16<<<dim3(DD / 128, M / 128, 4), 512, 0, stream>>>(
            hb16, w2l, nullptr, part, nullptr, nullptr, nullptr, nullptr, nullptr,
            M, DD, FFD / 4, 3);

        // 7. x = LN(x + Σpart + b2)
        ln_kernel<<<M, 256, 0, stream>>>(xbuf, part, b2l,
                                         ln2w + (size_t)l * DD, ln2b + (size_t)l * DD, xb16);
    }

    hipMemcpyAsync(out_x, xbuf, (size_t)BSD * sizeof(float),
                   hipMemcpyDeviceToDevice, stream);
}

// Round 8
// 1284.036 us; speedup vs baseline: 7.2791x; 1.0548x over previous
//
#include <hip/hip_runtime.h>
#include <cstdint>
#include <cstddef>
#include <math.h>

// Problem dims (fixed)
#define LL  8
#define BB  2
#define SS  1024
#define DD  1024
#define HH  16
#define HD  64
#define FFD 4096
#define BSD (BB*SS*DD)   // 2,097,152

typedef __attribute__((ext_vector_type(4))) float f32x4;
typedef __attribute__((ext_vector_type(8))) short bf16x8;
typedef __attribute__((ext_vector_type(4))) short bf16x4;

__device__ __forceinline__ unsigned short f2bf(float f) {
    unsigned u = __float_as_uint(f);
    unsigned r = (u + 0x7fffu + ((u >> 16) & 1u)) >> 16;   // RTN-even
    return (unsigned short)r;
}
__device__ __forceinline__ float bf2f(unsigned short u) {
    return __uint_as_float((unsigned)u << 16);
}

#define GLD16(gsrc, ldst) \
    __builtin_amdgcn_global_load_lds((const __attribute__((address_space(1))) void*)(gsrc), \
                                     (__attribute__((address_space(3))) void*)(ldst), 16, 0, 0)

// ---------------------------------------------------------------------------
// f32 -> bf16 elementwise convert (4 elems/thread)
// ---------------------------------------------------------------------------
__global__ __launch_bounds__(256)
void cvt_bf16(const float* __restrict__ in, unsigned short* __restrict__ out)
{
    size_t i = (size_t)blockIdx.x * 256 + threadIdx.x;
    float4 v = *(const float4*)(in + i * 4);
    ushort4 o;
    o.x = f2bf(v.x); o.y = f2bf(v.y); o.z = f2bf(v.z); o.w = f2bf(v.w);
    *(ushort4*)(out + i * 4) = o;
}

// x_in -> xbuf (f32 copy) + xb16 (bf16 copy), one pass
__global__ __launch_bounds__(256)
void cvt_x(const float* __restrict__ in, float* __restrict__ outf,
           unsigned short* __restrict__ outb)
{
    size_t i = (size_t)blockIdx.x * 256 + threadIdx.x;
    float4 v = *(const float4*)(in + i * 4);
    *(float4*)(outf + i * 4) = v;
    ushort4 o;
    o.x = f2bf(v.x); o.y = f2bf(v.y); o.z = f2bf(v.z); o.w = f2bf(v.w);
    *(ushort4*)(outb + i * 4) = o;
}

// ---------------------------------------------------------------------------
// bf16 MFMA GEMM, double-buffered BK=64, counted vmcnt (T3/T4), T2 swizzle.
// 128x128 tile, 512 thr = 8 waves (2Mx4N), wave 64x32 out (4x2 frags).
// vmcnt ledger: prologue 8 in flight; steady vmcnt(4); final iter vmcnt(0).
// mode 1: relu -> bf16 Cb      mode 2: QKV split (q bf16 / k,v f32+bf16)
// mode 3: bf16 partial -> Cb + z*M*N (split-K; LN fuses combine+bias)
// ---------------------------------------------------------------------------
__global__ __launch_bounds__(512)
void gemm_bf16(const unsigned short* __restrict__ A, const unsigned short* __restrict__ W,
               const float* __restrict__ bias,
               float* __restrict__ C, unsigned short* __restrict__ Cb,
               float* __restrict__ Ck, float* __restrict__ Cv,
               unsigned short* __restrict__ Kb16, unsigned short* __restrict__ Vb16,
               int M, int N, int klen, int mode)
{
    __shared__ unsigned short lds[2][2 * 128 * 64];   // [dbuf][A(8192) | W(8192)]

    const int tid  = threadIdx.x;
    const int m0   = blockIdx.y * 128;
    const int n0   = blockIdx.x * 128;
    const int kbase= blockIdx.z * klen;
    const int lane = tid & 63;
    const int w    = tid >> 6;          // 0..7
    const int wr   = w >> 2;            // 0..1 (M half)
    const int wc   = w & 3;             // 0..3 (N quarter)
    const int lr   = lane & 15;
    const int kq   = lane >> 4;

    const int K = (mode == 3) ? (klen * gridDim.z) : klen;   // row stride of A/W
    const int T = klen >> 6;                                  // # BK=64 tiles

    // Staging: chunk c = tid + i*512; row = c>>3, phys chunk pc = c&7,
    // logical col chunk lc = pc ^ (row&7) (XOR involution = read side).
    const int srow0 = tid >> 3;
    const int spc0  = tid & 7;
    const int slc0  = spc0 ^ (srow0 & 7);
    const int srow1 = (tid + 512) >> 3;
    const int spc1  = (tid + 512) & 7;
    const int slc1  = spc1 ^ (srow1 & 7);

    #define STAGE_TILE(ti, dst)                                                   \
        do {                                                                      \
            const int kc = kbase + (ti) * 64;                                     \
            GLD16(A + (size_t)(m0 + srow0) * K + kc + slc0 * 8, (dst) + tid * 8); \
            GLD16(A + (size_t)(m0 + srow1) * K + kc + slc1 * 8, (dst) + 4096 + tid * 8); \
            GLD16(W + (size_t)(n0 + srow0) * K + kc + slc0 * 8, (dst) + 8192 + tid * 8); \
            GLD16(W + (size_t)(n0 + srow1) * K + kc + slc1 * 8, (dst) + 12288 + tid * 8); \
        } while (0)

    f32x4 acc[4][2];
    #pragma unroll
    for (int i = 0; i < 4; ++i)
        #pragma unroll
        for (int j = 0; j < 2; ++j) {
            f32x4 z = {0.f, 0.f, 0.f, 0.f};
            acc[i][j] = z;
        }

    STAGE_TILE(0, lds[0]);
    STAGE_TILE(1, lds[1]);

    for (int t = 0; t < T; ++t) {
        unsigned short* cb = lds[t & 1];

        if (t == T - 1) {
            asm volatile("s_waitcnt vmcnt(0)\n\ts_barrier" ::: "memory");
        } else {
            asm volatile("s_waitcnt vmcnt(4)\n\ts_barrier" ::: "memory");
        }

        bf16x8 a[4], b[2];
        #pragma unroll
        for (int mf = 0; mf < 4; ++mf) {
            const int r = wr * 64 + mf * 16 + lr;
            const int pc = kq ^ (r & 7);
            a[mf] = *(const bf16x8*)(cb + r * 64 + pc * 8);
        }
        #pragma unroll
        for (int nf = 0; nf < 2; ++nf) {
            const int r = wc * 32 + nf * 16 + lr;
            const int pc = kq ^ (r & 7);
            b[nf] = *(const bf16x8*)(cb + 8192 + r * 64 + pc * 8);
        }
        bf16x8 a2[4], b2[2];
        #pragma unroll
        for (int mf = 0; mf < 4; ++mf) {
            const int r = wr * 64 + mf * 16 + lr;
            const int pc = (4 + kq) ^ (r & 7);
            a2[mf] = *(const bf16x8*)(cb + r * 64 + pc * 8);
        }
        #pragma unroll
        for (int nf = 0; nf < 2; ++nf) {
            const int r = wc * 32 + nf * 16 + lr;
            const int pc = (4 + kq) ^ (r & 7);
            b2[nf] = *(const bf16x8*)(cb + 8192 + r * 64 + pc * 8);
        }

        asm volatile("s_waitcnt lgkmcnt(0)\n\ts_barrier" ::: "memory");

        if (t + 2 < T) STAGE_TILE(t + 2, cb);
        __builtin_amdgcn_sched_barrier(0);

        __builtin_amdgcn_s_setprio(1);
        #pragma unroll
        for (int mf = 0; mf < 4; ++mf)
            #pragma unroll
            for (int nf = 0; nf < 2; ++nf)
                acc[mf][nf] = __builtin_amdgcn_mfma_f32_16x16x32_bf16(
                    a[mf], b[nf], acc[mf][nf], 0, 0, 0);
        #pragma unroll
        for (int mf = 0; mf < 4; ++mf)
            #pragma unroll
            for (int nf = 0; nf < 2; ++nf)
                acc[mf][nf] = __builtin_amdgcn_mfma_f32_16x16x32_bf16(
                    a2[mf], b2[nf], acc[mf][nf], 0, 0, 0);
        __builtin_amdgcn_s_setprio(0);
    }
    #undef STAGE_TILE

    // Epilogue. C/D layout: col = lane&15, row = (lane>>4)*4 + reg
    const int seg = n0 >> 10;
    #pragma unroll
    for (int nf = 0; nf < 2; ++nf) {
        const int cl = wc * 32 + nf * 16 + lr;
        const float bv = (mode == 3) ? 0.f : bias[n0 + cl];
        #pragma unroll
        for (int mf = 0; mf < 4; ++mf) {
            #pragma unroll
            for (int r = 0; r < 4; ++r) {
                const int row = m0 + wr * 64 + mf * 16 + kq * 4 + r;
                const float val = acc[mf][nf][r] + bv;
                if (mode == 2) {
                    const int col = (n0 & 1023) + cl;
                    float* dstf = (seg == 1) ? Ck : ((seg == 2) ? Cv : nullptr);
                    unsigned short* dstb = (seg == 0) ? Cb : ((seg == 1) ? Kb16 : Vb16);
                    if (dstf) dstf[(size_t)row * DD + col] = val;
                    dstb[(size_t)row * DD + col] = f2bf(val);
                } else if (mode == 1) {
                    Cb[(size_t)row * N + n0 + cl] = f2bf(fmaxf(val, 0.f));
                } else {   // mode 3: bf16 partial
                    Cb[(size_t)blockIdx.z * M * N + (size_t)row * N + n0 + cl] = f2bf(val);
                }
            }
        }
    }
}

// ---------------------------------------------------------------------------
// MFMA causal flash attention. Block = (128 q-rows, h, b), 512 thr = 8 waves;
// wave w owns q rows [w*16, w*16+16). K/Vt staged once per 64-key chunk for
// all 8 waves (2x reuse vs QBLK=64). Causal mask computed globally and
// applied unconditionally (no-op for pre-diagonal chunks).
// ---------------------------------------------------------------------------
__global__ __launch_bounds__(512)
void attn_mfma(const unsigned short* __restrict__ Qb, const unsigned short* __restrict__ Kb,
               const unsigned short* __restrict__ Vb, unsigned short* __restrict__ ctxb)
{
    const int qt = blockIdx.x;      // q-tile 0..7 (128 rows each)
    const int h  = blockIdx.y;
    const int b  = blockIdx.z;
    const int tid  = threadIdx.x;
    const int lane = tid & 63;
    const int w    = tid >> 6;      // 0..7
    const int lr   = lane & 15;
    const int hi   = lane >> 4;

    __shared__ unsigned short smem[(64 + 64 + 8 * 16) * 68];   // 34816 B
    unsigned short* Ks = smem;                           // [64][68] key-major
    unsigned short* Vt = smem + 64 * 68;                 // [64][68] d-major
    unsigned short* Pl = smem + 128 * 68 + w * 16 * 68;  // per-wave [16][68]

    const int qg0 = qt * 128 + w * 16;   // wave's first q row

    bf16x8 qa[2];
    {
        const unsigned short* qp = Qb + ((size_t)(b * SS + qg0 + lr)) * DD + h * HD;
        qa[0] = *(const bf16x8*)(qp + hi * 8);
        qa[1] = *(const bf16x8*)(qp + 32 + hi * 8);
    }

    f32x4 accO[4];
    #pragma unroll
    for (int t = 0; t < 4; ++t) { f32x4 z = {0.f,0.f,0.f,0.f}; accO[t] = z; }
    float m_run[4], l_run[4];
    #pragma unroll
    for (int r = 0; r < 4; ++r) { m_run[r] = -INFINITY; l_run[r] = 0.f; }

    const int nch = 2 * qt + 2;
    for (int c = 0; c < nch; ++c) {
        __syncthreads();
        const unsigned short* kb = Kb + ((size_t)(b * SS + c * 64)) * DD + h * HD;
        const unsigned short* vb = Vb + ((size_t)(b * SS + c * 64)) * DD + h * HD;
        {
            // K: 512 threads cover 64 rows x 8 chunks in one pass
            int r  = tid >> 3, ch = tid & 7;
            bf16x8 kv = *(const bf16x8*)(kb + (size_t)r * DD + ch * 8);
            *(bf16x4*)(Ks + r * 68 + ch * 8)     = __builtin_shufflevector(kv, kv, 0,1,2,3);
            *(bf16x4*)(Ks + r * 68 + ch * 8 + 4) = __builtin_shufflevector(kv, kv, 4,5,6,7);
            // V transposed: k = tid&63, d0 = (tid>>6)*8
            int k  = tid & 63, d0 = (tid >> 6) * 8;
            bf16x8 vv = *(const bf16x8*)(vb + (size_t)k * DD + d0);
            #pragma unroll
            for (int j = 0; j < 8; ++j)
                Vt[(d0 + j) * 68 + k] = (unsigned short)vv[j];
        }
        __syncthreads();

        f32x4 sa[4];
        #pragma unroll
        for (int t = 0; t < 4; ++t) { f32x4 z = {0.f,0.f,0.f,0.f}; sa[t] = z; }
        #pragma unroll
        for (int t = 0; t < 4; ++t) {
            #pragma unroll
            for (int s = 0; s < 2; ++s) {
                const unsigned short* bp = Ks + (t * 16 + lr) * 68 + s * 32 + hi * 8;
                bf16x4 b0 = *(const bf16x4*)bp;
                bf16x4 b1 = *(const bf16x4*)(bp + 4);
                bf16x8 bb = __builtin_shufflevector(b0, b1, 0,1,2,3,4,5,6,7);
                sa[t] = __builtin_amdgcn_mfma_f32_16x16x32_bf16(qa[s], bb, sa[t], 0, 0, 0);
            }
        }
        // scale + global causal mask (no-op for fully pre-diagonal chunks)
        #pragma unroll
        for (int t = 0; t < 4; ++t) {
            #pragma unroll
            for (int r = 0; r < 4; ++r) {
                const int kg = c * 64 + t * 16 + lr;
                const int qg = qg0 + hi * 4 + r;
                sa[t][r] = (kg > qg) ? -1e30f : sa[t][r] * 0.125f;
            }
        }
        #pragma unroll
        for (int r = 0; r < 4; ++r) {
            float mx = fmaxf(fmaxf(sa[0][r], sa[1][r]), fmaxf(sa[2][r], sa[3][r]));
            mx = fmaxf(mx, __shfl_xor(mx, 1));
            mx = fmaxf(mx, __shfl_xor(mx, 2));
            mx = fmaxf(mx, __shfl_xor(mx, 4));
            mx = fmaxf(mx, __shfl_xor(mx, 8));
            const float mn = fmaxf(m_run[r], mx);
            float sum = 0.f;
            #pragma unroll
            for (int t = 0; t < 4; ++t) {
                float p = __expf(sa[t][r] - mn);
                sa[t][r] = p;
                sum += p;
            }
            sum += __shfl_xor(sum, 1);
            sum += __shfl_xor(sum, 2);
            sum += __shfl_xor(sum, 4);
            sum += __shfl_xor(sum, 8);
            const float sc = __expf(m_run[r] - mn);
            l_run[r] = l_run[r] * sc + sum;
            m_run[r] = mn;
            #pragma unroll
            for (int t = 0; t < 4; ++t) accO[t][r] *= sc;
        }
        #pragma unroll
        for (int t = 0; t < 4; ++t)
            #pragma unroll
            for (int r = 0; r < 4; ++r)
                Pl[(hi * 4 + r) * 68 + t * 16 + lr] = f2bf(sa[t][r]);

        #pragma unroll
        for (int s = 0; s < 2; ++s) {
            const unsigned short* ap = Pl + lr * 68 + s * 32 + hi * 8;
            bf16x4 a0 = *(const bf16x4*)ap;
            bf16x4 a1 = *(const bf16x4*)(ap + 4);
            bf16x8 aa = __builtin_shufflevector(a0, a1, 0,1,2,3,4,5,6,7);
            #pragma unroll
            for (int t = 0; t < 4; ++t) {
                const unsigned short* bp = Vt + (t * 16 + lr) * 68 + s * 32 + hi * 8;
                bf16x4 b0 = *(const bf16x4*)bp;
                bf16x4 b1 = *(const bf16x4*)(bp + 4);
                bf16x8 bb = __builtin_shufflevector(b0, b1, 0,1,2,3,4,5,6,7);
                accO[t] = __builtin_amdgcn_mfma_f32_16x16x32_bf16(aa, bb, accO[t], 0, 0, 0);
            }
        }
    }

    float inv[4];
    #pragma unroll
    for (int r = 0; r < 4; ++r) inv[r] = 1.f / l_run[r];

    __syncthreads();
    float* Of = (float*)smem;   // [128][68] f32 = 34816 B, overlays smem
    #pragma unroll
    for (int t = 0; t < 4; ++t)
        #pragma unroll
        for (int r = 0; r < 4; ++r)
            Of[(w * 16 + hi * 4 + r) * 68 + t * 16 + lr] = accO[t][r] * inv[r];
    __syncthreads();
    #pragma unroll
    for (int i = 0; i < 2; ++i) {
        int e = tid + i * 512;
        int r = e >> 3, ch = e & 7;
        const float* src = Of + r * 68 + ch * 8;
        float4 v0 = *(const float4*)(src);
        float4 v1 = *(const float4*)(src + 4);
        bf16x8 o;
        o[0] = (short)f2bf(v0.x); o[1] = (short)f2bf(v0.y);
        o[2] = (short)f2bf(v0.z); o[3] = (short)f2bf(v0.w);
        o[4] = (short)f2bf(v1.x); o[5] = (short)f2bf(v1.y);
        o[6] = (short)f2bf(v1.z); o[7] = (short)f2bf(v1.w);
        *(bf16x8*)(ctxb + ((size_t)(b * SS + qt * 128 + r)) * DD + h * HD + ch * 8) = o;
    }
}

// ---------------------------------------------------------------------------
// x = LayerNorm(x + P0+P1+P2+P3 + bias) * w + b ; P = bf16 partials.
// Thread t handles d = t*4..t*4+3 (contiguous, vectorized).
// ---------------------------------------------------------------------------
__global__ __launch_bounds__(256)
void ln_kernel(float* __restrict__ x, const unsigned short* __restrict__ P,
               const float* __restrict__ bias,
               const float* __restrict__ w, const float* __restrict__ b,
               unsigned short* __restrict__ xb)
{
    const size_t PS = (size_t)BSD;   // partial stride
    const int row = blockIdx.x;
    const int t   = threadIdx.x;
    const int d0  = t * 4;
    float* xr = x + (size_t)row * DD;
    unsigned short* xbr = xb + (size_t)row * DD;
    const size_t base = (size_t)row * DD + d0;

    float4 xv = *(const float4*)(xr + d0);
    float4 bv = *(const float4*)(bias + d0);
    float z[4] = {xv.x + bv.x, xv.y + bv.y, xv.z + bv.z, xv.w + bv.w};
    #pragma unroll
    for (int p = 0; p < 4; ++p) {
        ushort4 pv = *(const ushort4*)(P + base + p * PS);
        z[0] += bf2f(pv.x); z[1] += bf2f(pv.y); z[2] += bf2f(pv.z); z[3] += bf2f(pv.w);
    }
    float s = z[0] + z[1] + z[2] + z[3];
    float ss = z[0]*z[0] + z[1]*z[1] + z[2]*z[2] + z[3]*z[3];

    #pragma unroll
    for (int off = 32; off; off >>= 1) {
        s  += __shfl_down(s, off);
        ss += __shfl_down(ss, off);
    }
    __shared__ float sbuf[4], ssbuf[4];
    const int wave = t >> 6, lane = t & 63;
    if (lane == 0) { sbuf[wave] = s; ssbuf[wave] = ss; }
    __syncthreads();
    if (t == 0) {
        float S = 0.f, SSum = 0.f;
        #pragma unroll
        for (int i = 0; i < 4; ++i) { S += sbuf[i]; SSum += ssbuf[i]; }
        float mean = S * (1.f / 1024.f);
        float var  = SSum * (1.f / 1024.f) - mean * mean;
        sbuf[0]  = mean;
        ssbuf[0] = rsqrtf(var + 1e-5f);
    }
    __syncthreads();
    const float mean = sbuf[0], rstd = ssbuf[0];

    float4 wv = *(const float4*)(w + d0);
    float4 bb = *(const float4*)(b + d0);
    float o0 = (z[0] - mean) * rstd * wv.x + bb.x;
    float o1 = (z[1] - mean) * rstd * wv.y + bb.y;
    float o2 = (z[2] - mean) * rstd * wv.z + bb.z;
    float o3 = (z[3] - mean) * rstd * wv.w + bb.w;
    *(float4*)(xr + d0) = make_float4(o0, o1, o2, o3);
    ushort4 ob4;
    ob4.x = f2bf(o0); ob4.y = f2bf(o1); ob4.z = f2bf(o2); ob4.w = f2bf(o3);
    *(ushort4*)(xbr + d0) = ob4;
}

// ---------------------------------------------------------------------------
extern "C" void kernel_launch(void* const* d_in, const int* in_sizes, int n_in,
                              void* d_out, int out_size, void* d_ws, size_t ws_size,
                              hipStream_t stream)
{
    const float* x_in  = (const float*)d_in[0];
    const float* qkv_w = (const float*)d_in[2];
    const float* qkv_b = (const float*)d_in[3];
    const float* out_w = (const float*)d_in[4];
    const float* out_b = (const float*)d_in[5];
    const float* w1    = (const float*)d_in[6];
    const float* b1    = (const float*)d_in[7];
    const float* w2    = (const float*)d_in[8];
    const float* b2    = (const float*)d_in[9];
    const float* ln1w  = (const float*)d_in[10];
    const float* ln1b  = (const float*)d_in[11];
    const float* ln2w  = (const float*)d_in[12];
    const float* ln2b  = (const float*)d_in[13];

    float* out_x = (float*)d_out;                    // [B,S,D]
    float* out_k = out_x + (size_t)BSD;              // [L,B,S,D]
    float* out_v = out_k + (size_t)LL * BSD;         // [L,B,S,D]

    const size_t MEG = 1024 * 1024;
    float* ws = (float*)d_ws;
    float*          xbuf  = ws;                               // 2M f32 (8 MB)
    unsigned short* part16= (unsigned short*)(ws + 2 * MEG);  // 4 x 2M bf16 (16 MB)
    unsigned short* xb16  = (unsigned short*)(ws + 6 * MEG);  // 2M bf16
    unsigned short* ctxb  = (unsigned short*)(ws + 7 * MEG);  // 2M bf16
    unsigned short* hb16  = (unsigned short*)(ws + 8 * MEG);  // 8M bf16 (16 MB)
    unsigned short* qb16  = hb16;                             // aliases (disjoint lifetime)
    unsigned short* kb16  = hb16 + 2 * MEG;
    unsigned short* vb16  = hb16 + 4 * MEG;
    unsigned short* wAll  = (unsigned short*)(ws + 12 * MEG); // 96M bf16 (192 MB)

    unsigned short* qkvW = wAll;                     // 24M
    unsigned short* outW = wAll + 24 * MEG;          //  8M
    unsigned short* w1W  = wAll + 32 * MEG;          // 32M
    unsigned short* w2W  = wAll + 64 * MEG;          // 32M

    cvt_bf16<<<24 * MEG / 1024, 256, 0, stream>>>(qkv_w, qkvW);
    cvt_bf16<<< 8 * MEG / 1024, 256, 0, stream>>>(out_w, outW);
    cvt_bf16<<<32 * MEG / 1024, 256, 0, stream>>>(w1,    w1W);
    cvt_bf16<<<32 * MEG / 1024, 256, 0, stream>>>(w2,    w2W);
    cvt_x<<<BSD / 1024, 256, 0, stream>>>(x_in, xbuf, xb16);

    const int M = BB * SS;   // 2048

    for (int l = 0; l < LL; ++l) {
        const float* qb  = qkv_b + (size_t)l * 3 * DD;
        const float* ob  = out_b + (size_t)l * DD;
        const float* b1l = b1    + (size_t)l * FFD;
        const float* b2l = b2    + (size_t)l * DD;
        const unsigned short* qwl = qkvW + (size_t)l * 3 * DD * DD;
        const unsigned short* owl = outW + (size_t)l * DD * DD;
        const unsigned short* w1l = w1W  + (size_t)l * FFD * DD;
        const unsigned short* w2l = w2W  + (size_t)l * DD * FFD;
        float* kc = out_k + (size_t)l * BSD;
        float* vc = out_v + (size_t)l * BSD;

        // 1. QKV projection (full K): q/k/v bf16 + f32 caches
        gemm_bf16<<<dim3(3 * DD / 128, M / 128, 1), 512, 0, stream>>>(
            xb16, qwl, qb, nullptr, qb16, kc, vc, kb16, vb16, M, 3 * DD, DD, 2);

        // 2. MFMA causal attention -> bf16 ctx (128-row q-tiles)
        attn_mfma<<<dim3(SS / 128, HH, BB), 512, 0, stream>>>(qb16, kb16, vb16, ctxb);

        // 3. output projection, split-K x4 -> bf16 partials
        gemm_bf16<<<dim3(DD / 128, M / 128, 4), 512, 0, stream>>>(
            ctxb, owl, nullptr, nullptr, part16, nullptr, nullptr, nullptr, nullptr,
            M, DD, DD / 4, 3);

        // 4. x = LN(x + Σpart + ob)
        ln_kernel<<<M, 256, 0, stream>>>(xbuf, part16, ob,
                                         ln1w + (size_t)l * DD, ln1b + (size_t)l * DD, xb16);

        // 5. h = relu(x @ w1^T + b1) -> bf16
        gemm_bf16<<<dim3(FFD / 128, M / 128, 1), 512, 0, stream>>>(
            xb16, w1l, b1l, nullptr, hb16, nullptr, nullptr, nullptr, nullptr,
            M, FFD, DD, 1);

        // 6. mlp = h @ w2^T, split-K x4 -> bf16 partials
        gemm_bf16<<<dim3(DD / 128, M / 128, 4), 512, 0, stream>>>(
            hb16, w2l, nullptr, nullptr, part16, nullptr, nullptr, nullptr, nullptr,
            M, DD, FFD / 4, 3);

        // 7. x = LN(x + Σpart + b2)
        ln_kernel<<<M, 256, 0, stream>>>(xbuf, part16, b2l,
                                         ln2w + (size_t)l * DD, ln2b + (size_t)l * DD, xb16);
    }

    hipMemcpyAsync(out_x, xbuf, (size_t)BSD * sizeof(float),
                   hipMemcpyDeviceToDevice, stream);
}

// Round 9
// 1246.453 us; speedup vs baseline: 7.4986x; 1.0302x over previous
//
#include <hip/hip_runtime.h>
#include <cstdint>
#include <cstddef>
#include <math.h>

// Problem dims (fixed)
#define LL  8
#define BB  2
#define SS  1024
#define DD  1024
#define HH  16
#define HD  64
#define FFD 4096
#define BSD (BB*SS*DD)   // 2,097,152

typedef __attribute__((ext_vector_type(4))) float f32x4;
typedef __attribute__((ext_vector_type(8))) short bf16x8;
typedef __attribute__((ext_vector_type(4))) short bf16x4;

__device__ __forceinline__ unsigned short f2bf(float f) {
    unsigned u = __float_as_uint(f);
    unsigned r = (u + 0x7fffu + ((u >> 16) & 1u)) >> 16;   // RTN-even
    return (unsigned short)r;
}
__device__ __forceinline__ float bf2f(unsigned short u) {
    return __uint_as_float((unsigned)u << 16);
}

#define GLD16(gsrc, ldst) \
    __builtin_amdgcn_global_load_lds((const __attribute__((address_space(1))) void*)(gsrc), \
                                     (__attribute__((address_space(3))) void*)(ldst), 16, 0, 0)

// XCD-aware bijective swizzle of the flattened xy block index (nwg % 8 == 0).
__device__ __forceinline__ void xcd_swizzle(int& bx, int& by)
{
    const int nx  = gridDim.x;
    const int nwg = nx * gridDim.y;
    const int flat = by * nx + bx;
    const int cpx = nwg >> 3;                 // chunks per XCD
    const int swz = (flat & 7) * cpx + (flat >> 3);
    bx = swz % nx;
    by = swz / nx;
}

// ---------------------------------------------------------------------------
// f32 -> bf16 elementwise convert (4 elems/thread)
// ---------------------------------------------------------------------------
__global__ __launch_bounds__(256)
void cvt_bf16(const float* __restrict__ in, unsigned short* __restrict__ out)
{
    size_t i = (size_t)blockIdx.x * 256 + threadIdx.x;
    float4 v = *(const float4*)(in + i * 4);
    ushort4 o;
    o.x = f2bf(v.x); o.y = f2bf(v.y); o.z = f2bf(v.z); o.w = f2bf(v.w);
    *(ushort4*)(out + i * 4) = o;
}

// x_in -> xbuf (f32 copy) + xb16 (bf16 copy), one pass
__global__ __launch_bounds__(256)
void cvt_x(const float* __restrict__ in, float* __restrict__ outf,
           unsigned short* __restrict__ outb)
{
    size_t i = (size_t)blockIdx.x * 256 + threadIdx.x;
    float4 v = *(const float4*)(in + i * 4);
    *(float4*)(outf + i * 4) = v;
    ushort4 o;
    o.x = f2bf(v.x); o.y = f2bf(v.y); o.z = f2bf(v.z); o.w = f2bf(v.w);
    *(ushort4*)(outb + i * 4) = o;
}

// ---------------------------------------------------------------------------
// bf16 MFMA GEMM, double-buffered BK=64, counted vmcnt (T3/T4), T2 swizzle,
// T1 XCD block swizzle. 128x128 tile, 512 thr = 8 waves (2Mx4N).
// vmcnt ledger: prologue 8 in flight; steady vmcnt(4); final iter vmcnt(0).
// mode 1: relu -> bf16 Cb      mode 2: QKV split (q bf16 / k,v f32+bf16)
// mode 3: bf16 partial -> Cb + z*M*N (split-K; LN fuses combine+bias)
// ---------------------------------------------------------------------------
__global__ __launch_bounds__(512)
void gemm_bf16(const unsigned short* __restrict__ A, const unsigned short* __restrict__ W,
               const float* __restrict__ bias,
               float* __restrict__ C, unsigned short* __restrict__ Cb,
               float* __restrict__ Ck, float* __restrict__ Cv,
               unsigned short* __restrict__ Kb16, unsigned short* __restrict__ Vb16,
               int M, int N, int klen, int mode)
{
    __shared__ unsigned short lds[2][2 * 128 * 64];   // [dbuf][A(8192) | W(8192)]

    int bx = blockIdx.x, by = blockIdx.y;
    xcd_swizzle(bx, by);

    const int tid  = threadIdx.x;
    const int m0   = by * 128;
    const int n0   = bx * 128;
    const int kbase= blockIdx.z * klen;
    const int lane = tid & 63;
    const int w    = tid >> 6;          // 0..7
    const int wr   = w >> 2;            // 0..1 (M half)
    const int wc   = w & 3;             // 0..3 (N quarter)
    const int lr   = lane & 15;
    const int kq   = lane >> 4;

    const int K = (mode == 3) ? (klen * gridDim.z) : klen;   // row stride of A/W
    const int T = klen >> 6;                                  // # BK=64 tiles

    // Staging: chunk c = tid + i*512; row = c>>3, phys chunk pc = c&7,
    // logical col chunk lc = pc ^ (row&7) (XOR involution = read side).
    const int srow0 = tid >> 3;
    const int spc0  = tid & 7;
    const int slc0  = spc0 ^ (srow0 & 7);
    const int srow1 = (tid + 512) >> 3;
    const int spc1  = (tid + 512) & 7;
    const int slc1  = spc1 ^ (srow1 & 7);

    #define STAGE_TILE(ti, dst)                                                   \
        do {                                                                      \
            const int kc = kbase + (ti) * 64;                                     \
            GLD16(A + (size_t)(m0 + srow0) * K + kc + slc0 * 8, (dst) + tid * 8); \
            GLD16(A + (size_t)(m0 + srow1) * K + kc + slc1 * 8, (dst) + 4096 + tid * 8); \
            GLD16(W + (size_t)(n0 + srow0) * K + kc + slc0 * 8, (dst) + 8192 + tid * 8); \
            GLD16(W + (size_t)(n0 + srow1) * K + kc + slc1 * 8, (dst) + 12288 + tid * 8); \
        } while (0)

    f32x4 acc[4][2];
    #pragma unroll
    for (int i = 0; i < 4; ++i)
        #pragma unroll
        for (int j = 0; j < 2; ++j) {
            f32x4 z = {0.f, 0.f, 0.f, 0.f};
            acc[i][j] = z;
        }

    STAGE_TILE(0, lds[0]);
    STAGE_TILE(1, lds[1]);

    for (int t = 0; t < T; ++t) {
        unsigned short* cb = lds[t & 1];

        if (t == T - 1) {
            asm volatile("s_waitcnt vmcnt(0)\n\ts_barrier" ::: "memory");
        } else {
            asm volatile("s_waitcnt vmcnt(4)\n\ts_barrier" ::: "memory");
        }

        bf16x8 a[4], b[2];
        #pragma unroll
        for (int mf = 0; mf < 4; ++mf) {
            const int r = wr * 64 + mf * 16 + lr;
            const int pc = kq ^ (r & 7);
            a[mf] = *(const bf16x8*)(cb + r * 64 + pc * 8);
        }
        #pragma unroll
        for (int nf = 0; nf < 2; ++nf) {
            const int r = wc * 32 + nf * 16 + lr;
            const int pc = kq ^ (r & 7);
            b[nf] = *(const bf16x8*)(cb + 8192 + r * 64 + pc * 8);
        }
        bf16x8 a2[4], b2[2];
        #pragma unroll
        for (int mf = 0; mf < 4; ++mf) {
            const int r = wr * 64 + mf * 16 + lr;
            const int pc = (4 + kq) ^ (r & 7);
            a2[mf] = *(const bf16x8*)(cb + r * 64 + pc * 8);
        }
        #pragma unroll
        for (int nf = 0; nf < 2; ++nf) {
            const int r = wc * 32 + nf * 16 + lr;
            const int pc = (4 + kq) ^ (r & 7);
            b2[nf] = *(const bf16x8*)(cb + 8192 + r * 64 + pc * 8);
        }

        asm volatile("s_waitcnt lgkmcnt(0)\n\ts_barrier" ::: "memory");

        if (t + 2 < T) STAGE_TILE(t + 2, cb);
        __builtin_amdgcn_sched_barrier(0);

        __builtin_amdgcn_s_setprio(1);
        #pragma unroll
        for (int mf = 0; mf < 4; ++mf)
            #pragma unroll
            for (int nf = 0; nf < 2; ++nf)
                acc[mf][nf] = __builtin_amdgcn_mfma_f32_16x16x32_bf16(
                    a[mf], b[nf], acc[mf][nf], 0, 0, 0);
        #pragma unroll
        for (int mf = 0; mf < 4; ++mf)
            #pragma unroll
            for (int nf = 0; nf < 2; ++nf)
                acc[mf][nf] = __builtin_amdgcn_mfma_f32_16x16x32_bf16(
                    a2[mf], b2[nf], acc[mf][nf], 0, 0, 0);
        __builtin_amdgcn_s_setprio(0);
    }
    #undef STAGE_TILE

    // Epilogue. C/D layout: col = lane&15, row = (lane>>4)*4 + reg
    const int seg = n0 >> 10;
    #pragma unroll
    for (int nf = 0; nf < 2; ++nf) {
        const int cl = wc * 32 + nf * 16 + lr;
        const float bv = (mode == 3) ? 0.f : bias[n0 + cl];
        #pragma unroll
        for (int mf = 0; mf < 4; ++mf) {
            #pragma unroll
            for (int r = 0; r < 4; ++r) {
                const int row = m0 + wr * 64 + mf * 16 + kq * 4 + r;
                const float val = acc[mf][nf][r] + bv;
                if (mode == 2) {
                    const int col = (n0 & 1023) + cl;
                    float* dstf = (seg == 1) ? Ck : ((seg == 2) ? Cv : nullptr);
                    unsigned short* dstb = (seg == 0) ? Cb : ((seg == 1) ? Kb16 : Vb16);
                    if (dstf) dstf[(size_t)row * DD + col] = val;
                    dstb[(size_t)row * DD + col] = f2bf(val);
                } else if (mode == 1) {
                    Cb[(size_t)row * N + n0 + cl] = f2bf(fmaxf(val, 0.f));
                } else {   // mode 3: bf16 partial
                    Cb[(size_t)blockIdx.z * M * N + (size_t)row * N + n0 + cl] = f2bf(val);
                }
            }
        }
    }
}

// ---------------------------------------------------------------------------
// MFMA causal flash attention. Block = (128 q-rows, h, b), 512 thr = 8 waves;
// wave w owns q rows [w*16, w*16+16). KV-chunk = 128 keys: one stage/barrier/
// softmax round per 128 keys (halved vs 64). K[128][68], Vt[64][136],
// per-wave P[16][136]. Causal mask global (no-op pre-diagonal).
// ---------------------------------------------------------------------------
__global__ __launch_bounds__(512)
void attn_mfma(const unsigned short* __restrict__ Qb, const unsigned short* __restrict__ Kb,
               const unsigned short* __restrict__ Vb, unsigned short* __restrict__ ctxb)
{
    int bx = blockIdx.x, by = blockIdx.y;
    xcd_swizzle(bx, by);
    const int qt = bx;              // q-tile 0..7 (128 rows each)
    const int h  = by;
    const int b  = blockIdx.z;
    const int tid  = threadIdx.x;
    const int lane = tid & 63;
    const int w    = tid >> 6;      // 0..7
    const int lr   = lane & 15;
    const int hi   = lane >> 4;

    __shared__ unsigned short smem[128 * 68 + 64 * 136 + 8 * 16 * 136];  // 69632 B
    unsigned short* Ks = smem;                                  // [128][68] key-major
    unsigned short* Vt = smem + 128 * 68;                       // [64][136] d-major
    unsigned short* Pl = smem + 128 * 68 + 64 * 136 + w * 16 * 136; // per-wave [16][136]

    const int qg0 = qt * 128 + w * 16;   // wave's first q row

    bf16x8 qa[2];
    {
        const unsigned short* qp = Qb + ((size_t)(b * SS + qg0 + lr)) * DD + h * HD;
        qa[0] = *(const bf16x8*)(qp + hi * 8);
        qa[1] = *(const bf16x8*)(qp + 32 + hi * 8);
    }

    f32x4 accO[4];
    #pragma unroll
    for (int t = 0; t < 4; ++t) { f32x4 z = {0.f,0.f,0.f,0.f}; accO[t] = z; }
    float m_run[4], l_run[4];
    #pragma unroll
    for (int r = 0; r < 4; ++r) { m_run[r] = -INFINITY; l_run[r] = 0.f; }

    const int nch = qt + 1;     // 128-key chunks
    for (int c = 0; c < nch; ++c) {
        __syncthreads();
        const unsigned short* kb = Kb + ((size_t)(b * SS + c * 128)) * DD + h * HD;
        const unsigned short* vb = Vb + ((size_t)(b * SS + c * 128)) * DD + h * HD;
        #pragma unroll
        for (int i = 0; i < 2; ++i) {
            int e = tid + i * 512;
            // K: 128 rows x 8 chunks
            int r  = e >> 3, ch = e & 7;
            bf16x8 kv = *(const bf16x8*)(kb + (size_t)r * DD + ch * 8);
            *(bf16x4*)(Ks + r * 68 + ch * 8)     = __builtin_shufflevector(kv, kv, 0,1,2,3);
            *(bf16x4*)(Ks + r * 68 + ch * 8 + 4) = __builtin_shufflevector(kv, kv, 4,5,6,7);
            // V transposed: k = e&127, d0 = (e>>7)*8
            int k  = e & 127, d0 = (e >> 7) * 8;
            bf16x8 vv = *(const bf16x8*)(vb + (size_t)k * DD + d0);
            #pragma unroll
            for (int j = 0; j < 8; ++j)
                Vt[(d0 + j) * 136 + k] = (unsigned short)vv[j];
        }
        __syncthreads();

        // QK^T: 8 k-tiles of 16
        f32x4 sa[8];
        #pragma unroll
        for (int t = 0; t < 8; ++t) { f32x4 z = {0.f,0.f,0.f,0.f}; sa[t] = z; }
        #pragma unroll
        for (int t = 0; t < 8; ++t) {
            #pragma unroll
            for (int s = 0; s < 2; ++s) {
                const unsigned short* bp = Ks + (t * 16 + lr) * 68 + s * 32 + hi * 8;
                bf16x4 b0 = *(const bf16x4*)bp;
                bf16x4 b1 = *(const bf16x4*)(bp + 4);
                bf16x8 bb = __builtin_shufflevector(b0, b1, 0,1,2,3,4,5,6,7);
                sa[t] = __builtin_amdgcn_mfma_f32_16x16x32_bf16(qa[s], bb, sa[t], 0, 0, 0);
            }
        }
        // scale + global causal mask
        #pragma unroll
        for (int t = 0; t < 8; ++t) {
            #pragma unroll
            for (int r = 0; r < 4; ++r) {
                const int kg = c * 128 + t * 16 + lr;
                const int qg = qg0 + hi * 4 + r;
                sa[t][r] = (kg > qg) ? -1e30f : sa[t][r] * 0.125f;
            }
        }
        // online softmax (one round per 128 keys)
        #pragma unroll
        for (int r = 0; r < 4; ++r) {
            float mx = -INFINITY;
            #pragma unroll
            for (int t = 0; t < 8; ++t) mx = fmaxf(mx, sa[t][r]);
            mx = fmaxf(mx, __shfl_xor(mx, 1));
            mx = fmaxf(mx, __shfl_xor(mx, 2));
            mx = fmaxf(mx, __shfl_xor(mx, 4));
            mx = fmaxf(mx, __shfl_xor(mx, 8));
            const float mn = fmaxf(m_run[r], mx);
            float sum = 0.f;
            #pragma unroll
            for (int t = 0; t < 8; ++t) {
                float p = __expf(sa[t][r] - mn);
                sa[t][r] = p;
                sum += p;
            }
            sum += __shfl_xor(sum, 1);
            sum += __shfl_xor(sum, 2);
            sum += __shfl_xor(sum, 4);
            sum += __shfl_xor(sum, 8);
            const float sc = __expf(m_run[r] - mn);
            l_run[r] = l_run[r] * sc + sum;
            m_run[r] = mn;
            #pragma unroll
            for (int t = 0; t < 4; ++t) accO[t][r] *= sc;
        }
        #pragma unroll
        for (int t = 0; t < 8; ++t)
            #pragma unroll
            for (int r = 0; r < 4; ++r)
                Pl[(hi * 4 + r) * 136 + t * 16 + lr] = f2bf(sa[t][r]);

        // PV over 4 k-quarters of 32
        #pragma unroll
        for (int s = 0; s < 4; ++s) {
            const unsigned short* ap = Pl + lr * 136 + s * 32 + hi * 8;
            bf16x4 a0 = *(const bf16x4*)ap;
            bf16x4 a1 = *(const bf16x4*)(ap + 4);
            bf16x8 aa = __builtin_shufflevector(a0, a1, 0,1,2,3,4,5,6,7);
            #pragma unroll
            for (int t = 0; t < 4; ++t) {
                const unsigned short* bp = Vt + (t * 16 + lr) * 136 + s * 32 + hi * 8;
                bf16x4 b0 = *(const bf16x4*)bp;
                bf16x4 b1 = *(const bf16x4*)(bp + 4);
                bf16x8 bb = __builtin_shufflevector(b0, b1, 0,1,2,3,4,5,6,7);
                accO[t] = __builtin_amdgcn_mfma_f32_16x16x32_bf16(aa, bb, accO[t], 0, 0, 0);
            }
        }
    }

    float inv[4];
    #pragma unroll
    for (int r = 0; r < 4; ++r) inv[r] = 1.f / l_run[r];

    __syncthreads();
    float* Of = (float*)smem;   // [128][68] f32 = 34816 B, overlays smem
    #pragma unroll
    for (int t = 0; t < 4; ++t)
        #pragma unroll
        for (int r = 0; r < 4; ++r)
            Of[(w * 16 + hi * 4 + r) * 68 + t * 16 + lr] = accO[t][r] * inv[r];
    __syncthreads();
    #pragma unroll
    for (int i = 0; i < 2; ++i) {
        int e = tid + i * 512;
        int r = e >> 3, ch = e & 7;
        const float* src = Of + r * 68 + ch * 8;
        float4 v0 = *(const float4*)(src);
        float4 v1 = *(const float4*)(src + 4);
        bf16x8 o;
        o[0] = (short)f2bf(v0.x); o[1] = (short)f2bf(v0.y);
        o[2] = (short)f2bf(v0.z); o[3] = (short)f2bf(v0.w);
        o[4] = (short)f2bf(v1.x); o[5] = (short)f2bf(v1.y);
        o[6] = (short)f2bf(v1.z); o[7] = (short)f2bf(v1.w);
        *(bf16x8*)(ctxb + ((size_t)(b * SS + qt * 128 + r)) * DD + h * HD + ch * 8) = o;
    }
}

// ---------------------------------------------------------------------------
// x = LayerNorm(x + P0+P1+P2+P3 + bias) * w + b ; P = bf16 partials.
// ---------------------------------------------------------------------------
__global__ __launch_bounds__(256)
void ln_kernel(float* __restrict__ x, const unsigned short* __restrict__ P,
               const float* __restrict__ bias,
               const float* __restrict__ w, const float* __restrict__ b,
               unsigned short* __restrict__ xb)
{
    const size_t PS = (size_t)BSD;   // partial stride
    const int row = blockIdx.x;
    const int t   = threadIdx.x;
    const int d0  = t * 4;
    float* xr = x + (size_t)row * DD;
    unsigned short* xbr = xb + (size_t)row * DD;
    const size_t base = (size_t)row * DD + d0;

    float4 xv = *(const float4*)(xr + d0);
    float4 bv = *(const float4*)(bias + d0);
    float z[4] = {xv.x + bv.x, xv.y + bv.y, xv.z + bv.z, xv.w + bv.w};
    #pragma unroll
    for (int p = 0; p < 4; ++p) {
        ushort4 pv = *(const ushort4*)(P + base + p * PS);
        z[0] += bf2f(pv.x); z[1] += bf2f(pv.y); z[2] += bf2f(pv.z); z[3] += bf2f(pv.w);
    }
    float s = z[0] + z[1] + z[2] + z[3];
    float ss = z[0]*z[0] + z[1]*z[1] + z[2]*z[2] + z[3]*z[3];

    #pragma unroll
    for (int off = 32; off; off >>= 1) {
        s  += __shfl_down(s, off);
        ss += __shfl_down(ss, off);
    }
    __shared__ float sbuf[4], ssbuf[4];
    const int wave = t >> 6, lane = t & 63;
    if (lane == 0) { sbuf[wave] = s; ssbuf[wave] = ss; }
    __syncthreads();
    if (t == 0) {
        float S = 0.f, SSum = 0.f;
        #pragma unroll
        for (int i = 0; i < 4; ++i) { S += sbuf[i]; SSum += ssbuf[i]; }
        float mean = S * (1.f / 1024.f);
        float var  = SSum * (1.f / 1024.f) - mean * mean;
        sbuf[0]  = mean;
        ssbuf[0] = rsqrtf(var + 1e-5f);
    }
    __syncthreads();
    const float mean = sbuf[0], rstd = ssbuf[0];

    float4 wv = *(const float4*)(w + d0);
    float4 bb = *(const float4*)(b + d0);
    float o0 = (z[0] - mean) * rstd * wv.x + bb.x;
    float o1 = (z[1] - mean) * rstd * wv.y + bb.y;
    float o2 = (z[2] - mean) * rstd * wv.z + bb.z;
    float o3 = (z[3] - mean) * rstd * wv.w + bb.w;
    *(float4*)(xr + d0) = make_float4(o0, o1, o2, o3);
    ushort4 ob4;
    ob4.x = f2bf(o0); ob4.y = f2bf(o1); ob4.z = f2bf(o2); ob4.w = f2bf(o3);
    *(ushort4*)(xbr + d0) = ob4;
}

// ---------------------------------------------------------------------------
extern "C" void kernel_launch(void* const* d_in, const int* in_sizes, int n_in,
                              void* d_out, int out_size, void* d_ws, size_t ws_size,
                              hipStream_t stream)
{
    const float* x_in  = (const float*)d_in[0];
    const float* qkv_w = (const float*)d_in[2];
    const float* qkv_b = (const float*)d_in[3];
    const float* out_w = (const float*)d_in[4];
    const float* out_b = (const float*)d_in[5];
    const float* w1    = (const float*)d_in[6];
    const float* b1    = (const float*)d_in[7];
    const float* w2    = (const float*)d_in[8];
    const float* b2    = (const float*)d_in[9];
    const float* ln1w  = (const float*)d_in[10];
    const float* ln1b  = (const float*)d_in[11];
    const float* ln2w  = (const float*)d_in[12];
    const float* ln2b  = (const float*)d_in[13];

    float* out_x = (float*)d_out;                    // [B,S,D]
    float* out_k = out_x + (size_t)BSD;              // [L,B,S,D]
    float* out_v = out_k + (size_t)LL * BSD;         // [L,B,S,D]

    const size_t MEG = 1024 * 1024;
    float* ws = (float*)d_ws;
    float*          xbuf  = ws;                               // 2M f32 (8 MB)
    unsigned short* part16= (unsigned short*)(ws + 2 * MEG);  // 4 x 2M bf16 (16 MB)
    unsigned short* xb16  = (unsigned short*)(ws + 6 * MEG);  // 2M bf16
    unsigned short* ctxb  = (unsigned short*)(ws + 7 * MEG);  // 2M bf16
    unsigned short* hb16  = (unsigned short*)(ws + 8 * MEG);  // 8M bf16 (16 MB)
    unsigned short* qb16  = hb16;                             // aliases (disjoint lifetime)
    unsigned short* kb16  = hb16 + 2 * MEG;
    unsigned short* vb16  = hb16 + 4 * MEG;
    unsigned short* wAll  = (unsigned short*)(ws + 12 * MEG); // 96M bf16 (192 MB)

    unsigned short* qkvW = wAll;                     // 24M
    unsigned short* outW = wAll + 24 * MEG;          //  8M
    unsigned short* w1W  = wAll + 32 * MEG;          // 32M
    unsigned short* w2W  = wAll + 64 * MEG;          // 32M

    cvt_bf16<<<24 * MEG / 1024, 256, 0, stream>>>(qkv_w, qkvW);
    cvt_bf16<<< 8 * MEG / 1024, 256, 0, stream>>>(out_w, outW);
    cvt_bf16<<<32 * MEG / 1024, 256, 0, stream>>>(w1,    w1W);
    cvt_bf16<<<32 * MEG / 1024, 256, 0, stream>>>(w2,    w2W);
    cvt_x<<<BSD / 1024, 256, 0, stream>>>(x_in, xbuf, xb16);

    const int M = BB * SS;   // 2048

    for (int l = 0; l < LL; ++l) {
        const float* qb  = qkv_b + (size_t)l * 3 * DD;
        const float* ob  = out_b + (size_t)l * DD;
        const float* b1l = b1    + (size_t)l * FFD;
        const float* b2l = b2    + (size_t)l * DD;
        const unsigned short* qwl = qkvW + (size_t)l * 3 * DD * DD;
        const unsigned short* owl = outW + (size_t)l * DD * DD;
        const unsigned short* w1l = w1W  + (size_t)l * FFD * DD;
        const unsigned short* w2l = w2W  + (size_t)l * DD * FFD;
        float* kc = out_k + (size_t)l * BSD;
        float* vc = out_v + (size_t)l * BSD;

        // 1. QKV projection (full K): q/k/v bf16 + f32 caches
        gemm_bf16<<<dim3(3 * DD / 128, M / 128, 1), 512, 0, stream>>>(
            xb16, qwl, qb, nullptr, qb16, kc, vc, kb16, vb16, M, 3 * DD, DD, 2);

        // 2. MFMA causal attention -> bf16 ctx (128-row q-tiles, 128-key chunks)
        attn_mfma<<<dim3(SS / 128, HH, BB), 512, 0, stream>>>(qb16, kb16, vb16, ctxb);

        // 3. output projection, split-K x4 -> bf16 partials
        gemm_bf16<<<dim3(DD / 128, M / 128, 4), 512, 0, stream>>>(
            ctxb, owl, nullptr, nullptr, part16, nullptr, nullptr, nullptr, nullptr,
            M, DD, DD / 4, 3);

        // 4. x = LN(x + Σpart + ob)
        ln_kernel<<<M, 256, 0, stream>>>(xbuf, part16, ob,
                                         ln1w + (size_t)l * DD, ln1b + (size_t)l * DD, xb16);

        // 5. h = relu(x @ w1^T + b1) -> bf16
        gemm_bf16<<<dim3(FFD / 128, M / 128, 1), 512, 0, stream>>>(
            xb16, w1l, b1l, nullptr, hb16, nullptr, nullptr, nullptr, nullptr,
            M, FFD, DD, 1);

        // 6. mlp = h @ w2^T, split-K x4 -> bf16 partials
        gemm_bf16<<<dim3(DD / 128, M / 128, 4), 512, 0, stream>>>(
            hb16, w2l, nullptr, nullptr, part16, nullptr, nullptr, nullptr, nullptr,
            M, DD, FFD / 4, 3);

        // 7. x = LN(x + Σpart + b2)
        ln_kernel<<<M, 256, 0, stream>>>(xbuf, part16, b2l,
                                         ln2w + (size_t)l * DD, ln2b + (size_t)l * DD, xb16);
    }

    hipMemcpyAsync(out_x, xbuf, (size_t)BSD * sizeof(float),
                   hipMemcpyDeviceToDevice, stream);
}

// Round 10
// 1244.997 us; speedup vs baseline: 7.5073x; 1.0012x over previous
//
#include <hip/hip_runtime.h>
#include <cstdint>
#include <cstddef>
#include <math.h>

// Problem dims (fixed)
#define LL  8
#define BB  2
#define SS  1024
#define DD  1024
#define HH  16
#define HD  64
#define FFD 4096
#define BSD (BB*SS*DD)   // 2,097,152

typedef __attribute__((ext_vector_type(4))) float f32x4;
typedef __attribute__((ext_vector_type(8))) short bf16x8;
typedef __attribute__((ext_vector_type(4))) short bf16x4;

__device__ __forceinline__ unsigned short f2bf(float f) {
    unsigned u = __float_as_uint(f);
    unsigned r = (u + 0x7fffu + ((u >> 16) & 1u)) >> 16;   // RTN-even
    return (unsigned short)r;
}
__device__ __forceinline__ float bf2f(unsigned short u) {
    return __uint_as_float((unsigned)u << 16);
}

#define GLD16(gsrc, ldst) \
    __builtin_amdgcn_global_load_lds((const __attribute__((address_space(1))) void*)(gsrc), \
                                     (__attribute__((address_space(3))) void*)(ldst), 16, 0, 0)

// XCD-aware bijective swizzle of the flattened xy block index (nwg % 8 == 0).
__device__ __forceinline__ void xcd_swizzle(int& bx, int& by)
{
    const int nx  = gridDim.x;
    const int nwg = nx * gridDim.y;
    const int flat = by * nx + bx;
    const int cpx = nwg >> 3;                 // chunks per XCD
    const int swz = (flat & 7) * cpx + (flat >> 3);
    bx = swz % nx;
    by = swz / nx;
}

// ---------------------------------------------------------------------------
// f32 -> bf16 elementwise convert (4 elems/thread)
// ---------------------------------------------------------------------------
__global__ __launch_bounds__(256)
void cvt_bf16(const float* __restrict__ in, unsigned short* __restrict__ out)
{
    size_t i = (size_t)blockIdx.x * 256 + threadIdx.x;
    float4 v = *(const float4*)(in + i * 4);
    ushort4 o;
    o.x = f2bf(v.x); o.y = f2bf(v.y); o.z = f2bf(v.z); o.w = f2bf(v.w);
    *(ushort4*)(out + i * 4) = o;
}

// x_in -> xbuf (f32 copy) + xb16 (bf16 copy), one pass
__global__ __launch_bounds__(256)
void cvt_x(const float* __restrict__ in, float* __restrict__ outf,
           unsigned short* __restrict__ outb)
{
    size_t i = (size_t)blockIdx.x * 256 + threadIdx.x;
    float4 v = *(const float4*)(in + i * 4);
    *(float4*)(outf + i * 4) = v;
    ushort4 o;
    o.x = f2bf(v.x); o.y = f2bf(v.y); o.z = f2bf(v.z); o.w = f2bf(v.w);
    *(ushort4*)(outb + i * 4) = o;
}

// ---------------------------------------------------------------------------
// bf16 MFMA GEMM, double-buffered BK=64, counted vmcnt (T3/T4), T2 swizzle,
// T1 XCD block swizzle. 128x128 tile, 512 thr = 8 waves (2Mx4N).
// K-loop order (R10): ds_read x12 -> MFMA (compiler-counted lgkmcnt: half0
// MFMAs start after 6 reads, overlapping half1 reads) -> lgkmcnt(0)+barrier
// -> STAGE(t+2). vmcnt ledger unchanged: steady vmcnt(4), final vmcnt(0).
// mode 1: relu -> bf16 Cb      mode 2: QKV split (q bf16 / k,v f32+bf16)
// mode 3: bf16 partial -> Cb + z*M*N (split-K; LN fuses combine+bias)
// ---------------------------------------------------------------------------
__global__ __launch_bounds__(512)
void gemm_bf16(const unsigned short* __restrict__ A, const unsigned short* __restrict__ W,
               const float* __restrict__ bias,
               float* __restrict__ C, unsigned short* __restrict__ Cb,
               float* __restrict__ Ck, float* __restrict__ Cv,
               unsigned short* __restrict__ Kb16, unsigned short* __restrict__ Vb16,
               int M, int N, int klen, int mode)
{
    __shared__ unsigned short lds[2][2 * 128 * 64];   // [dbuf][A(8192) | W(8192)]

    int bx = blockIdx.x, by = blockIdx.y;
    xcd_swizzle(bx, by);

    const int tid  = threadIdx.x;
    const int m0   = by * 128;
    const int n0   = bx * 128;
    const int kbase= blockIdx.z * klen;
    const int lane = tid & 63;
    const int w    = tid >> 6;          // 0..7
    const int wr   = w >> 2;            // 0..1 (M half)
    const int wc   = w & 3;             // 0..3 (N quarter)
    const int lr   = lane & 15;
    const int kq   = lane >> 4;

    const int K = (mode == 3) ? (klen * gridDim.z) : klen;   // row stride of A/W
    const int T = klen >> 6;                                  // # BK=64 tiles

    // Staging: chunk c = tid + i*512; row = c>>3, phys chunk pc = c&7,
    // logical col chunk lc = pc ^ (row&7) (XOR involution = read side).
    const int srow0 = tid >> 3;
    const int spc0  = tid & 7;
    const int slc0  = spc0 ^ (srow0 & 7);
    const int srow1 = (tid + 512) >> 3;
    const int spc1  = (tid + 512) & 7;
    const int slc1  = spc1 ^ (srow1 & 7);

    #define STAGE_TILE(ti, dst)                                                   \
        do {                                                                      \
            const int kc = kbase + (ti) * 64;                                     \
            GLD16(A + (size_t)(m0 + srow0) * K + kc + slc0 * 8, (dst) + tid * 8); \
            GLD16(A + (size_t)(m0 + srow1) * K + kc + slc1 * 8, (dst) + 4096 + tid * 8); \
            GLD16(W + (size_t)(n0 + srow0) * K + kc + slc0 * 8, (dst) + 8192 + tid * 8); \
            GLD16(W + (size_t)(n0 + srow1) * K + kc + slc1 * 8, (dst) + 12288 + tid * 8); \
        } while (0)

    f32x4 acc[4][2];
    #pragma unroll
    for (int i = 0; i < 4; ++i)
        #pragma unroll
        for (int j = 0; j < 2; ++j) {
            f32x4 z = {0.f, 0.f, 0.f, 0.f};
            acc[i][j] = z;
        }

    STAGE_TILE(0, lds[0]);
    STAGE_TILE(1, lds[1]);

    for (int t = 0; t < T; ++t) {
        unsigned short* cb = lds[t & 1];

        if (t == T - 1) {
            asm volatile("s_waitcnt vmcnt(0)\n\ts_barrier" ::: "memory");
        } else {
            asm volatile("s_waitcnt vmcnt(4)\n\ts_barrier" ::: "memory");
        }

        // All 12 ds_reads issued up front; MFMA below uses compiler-counted
        // lgkmcnt so half-0 MFMAs overlap half-1 reads.
        bf16x8 a[4], b[2], a2[4], b2[2];
        #pragma unroll
        for (int mf = 0; mf < 4; ++mf) {
            const int r = wr * 64 + mf * 16 + lr;
            const int pc = kq ^ (r & 7);
            a[mf] = *(const bf16x8*)(cb + r * 64 + pc * 8);
        }
        #pragma unroll
        for (int nf = 0; nf < 2; ++nf) {
            const int r = wc * 32 + nf * 16 + lr;
            const int pc = kq ^ (r & 7);
            b[nf] = *(const bf16x8*)(cb + 8192 + r * 64 + pc * 8);
        }
        #pragma unroll
        for (int mf = 0; mf < 4; ++mf) {
            const int r = wr * 64 + mf * 16 + lr;
            const int pc = (4 + kq) ^ (r & 7);
            a2[mf] = *(const bf16x8*)(cb + r * 64 + pc * 8);
        }
        #pragma unroll
        for (int nf = 0; nf < 2; ++nf) {
            const int r = wc * 32 + nf * 16 + lr;
            const int pc = (4 + kq) ^ (r & 7);
            b2[nf] = *(const bf16x8*)(cb + 8192 + r * 64 + pc * 8);
        }

        __builtin_amdgcn_s_setprio(1);
        #pragma unroll
        for (int mf = 0; mf < 4; ++mf)
            #pragma unroll
            for (int nf = 0; nf < 2; ++nf)
                acc[mf][nf] = __builtin_amdgcn_mfma_f32_16x16x32_bf16(
                    a[mf], b[nf], acc[mf][nf], 0, 0, 0);
        #pragma unroll
        for (int mf = 0; mf < 4; ++mf)
            #pragma unroll
            for (int nf = 0; nf < 2; ++nf)
                acc[mf][nf] = __builtin_amdgcn_mfma_f32_16x16x32_bf16(
                    a2[mf], b2[nf], acc[mf][nf], 0, 0, 0);
        __builtin_amdgcn_s_setprio(0);

        // all waves' reads of this buffer consumed -> safe to overwrite
        asm volatile("s_waitcnt lgkmcnt(0)\n\ts_barrier" ::: "memory");
        if (t + 2 < T) STAGE_TILE(t + 2, cb);
    }
    #undef STAGE_TILE

    // Epilogue. C/D layout: col = lane&15, row = (lane>>4)*4 + reg
    const int seg = n0 >> 10;
    #pragma unroll
    for (int nf = 0; nf < 2; ++nf) {
        const int cl = wc * 32 + nf * 16 + lr;
        const float bv = (mode == 3) ? 0.f : bias[n0 + cl];
        #pragma unroll
        for (int mf = 0; mf < 4; ++mf) {
            #pragma unroll
            for (int r = 0; r < 4; ++r) {
                const int row = m0 + wr * 64 + mf * 16 + kq * 4 + r;
                const float val = acc[mf][nf][r] + bv;
                if (mode == 2) {
                    const int col = (n0 & 1023) + cl;
                    float* dstf = (seg == 1) ? Ck : ((seg == 2) ? Cv : nullptr);
                    unsigned short* dstb = (seg == 0) ? Cb : ((seg == 1) ? Kb16 : Vb16);
                    if (dstf) dstf[(size_t)row * DD + col] = val;
                    dstb[(size_t)row * DD + col] = f2bf(val);
                } else if (mode == 1) {
                    Cb[(size_t)row * N + n0 + cl] = f2bf(fmaxf(val, 0.f));
                } else {   // mode 3: bf16 partial
                    Cb[(size_t)blockIdx.z * M * N + (size_t)row * N + n0 + cl] = f2bf(val);
                }
            }
        }
    }
}

// ---------------------------------------------------------------------------
// MFMA causal flash attention (unchanged from R9). Block = (128 q, h, b),
// 512 thr = 8 waves; KV-chunk 128; K[128][68], Vt[64][136], P[16][136].
// ---------------------------------------------------------------------------
__global__ __launch_bounds__(512)
void attn_mfma(const unsigned short* __restrict__ Qb, const unsigned short* __restrict__ Kb,
               const unsigned short* __restrict__ Vb, unsigned short* __restrict__ ctxb)
{
    int bx = blockIdx.x, by = blockIdx.y;
    xcd_swizzle(bx, by);
    const int qt = bx;              // q-tile 0..7 (128 rows each)
    const int h  = by;
    const int b  = blockIdx.z;
    const int tid  = threadIdx.x;
    const int lane = tid & 63;
    const int w    = tid >> 6;      // 0..7
    const int lr   = lane & 15;
    const int hi   = lane >> 4;

    __shared__ unsigned short smem[128 * 68 + 64 * 136 + 8 * 16 * 136];  // 69632 B
    unsigned short* Ks = smem;                                  // [128][68] key-major
    unsigned short* Vt = smem + 128 * 68;                       // [64][136] d-major
    unsigned short* Pl = smem + 128 * 68 + 64 * 136 + w * 16 * 136; // per-wave [16][136]

    const int qg0 = qt * 128 + w * 16;   // wave's first q row

    bf16x8 qa[2];
    {
        const unsigned short* qp = Qb + ((size_t)(b * SS + qg0 + lr)) * DD + h * HD;
        qa[0] = *(const bf16x8*)(qp + hi * 8);
        qa[1] = *(const bf16x8*)(qp + 32 + hi * 8);
    }

    f32x4 accO[4];
    #pragma unroll
    for (int t = 0; t < 4; ++t) { f32x4 z = {0.f,0.f,0.f,0.f}; accO[t] = z; }
    float m_run[4], l_run[4];
    #pragma unroll
    for (int r = 0; r < 4; ++r) { m_run[r] = -INFINITY; l_run[r] = 0.f; }

    const int nch = qt + 1;     // 128-key chunks
    for (int c = 0; c < nch; ++c) {
        __syncthreads();
        const unsigned short* kb = Kb + ((size_t)(b * SS + c * 128)) * DD + h * HD;
        const unsigned short* vb = Vb + ((size_t)(b * SS + c * 128)) * DD + h * HD;
        #pragma unroll
        for (int i = 0; i < 2; ++i) {
            int e = tid + i * 512;
            int r  = e >> 3, ch = e & 7;
            bf16x8 kv = *(const bf16x8*)(kb + (size_t)r * DD + ch * 8);
            *(bf16x4*)(Ks + r * 68 + ch * 8)     = __builtin_shufflevector(kv, kv, 0,1,2,3);
            *(bf16x4*)(Ks + r * 68 + ch * 8 + 4) = __builtin_shufflevector(kv, kv, 4,5,6,7);
            int k  = e & 127, d0 = (e >> 7) * 8;
            bf16x8 vv = *(const bf16x8*)(vb + (size_t)k * DD + d0);
            #pragma unroll
            for (int j = 0; j < 8; ++j)
                Vt[(d0 + j) * 136 + k] = (unsigned short)vv[j];
        }
        __syncthreads();

        // QK^T: 8 k-tiles of 16
        f32x4 sa[8];
        #pragma unroll
        for (int t = 0; t < 8; ++t) { f32x4 z = {0.f,0.f,0.f,0.f}; sa[t] = z; }
        #pragma unroll
        for (int t = 0; t < 8; ++t) {
            #pragma unroll
            for (int s = 0; s < 2; ++s) {
                const unsigned short* bp = Ks + (t * 16 + lr) * 68 + s * 32 + hi * 8;
                bf16x4 b0 = *(const bf16x4*)bp;
                bf16x4 b1 = *(const bf16x4*)(bp + 4);
                bf16x8 bb = __builtin_shufflevector(b0, b1, 0,1,2,3,4,5,6,7);
                sa[t] = __builtin_amdgcn_mfma_f32_16x16x32_bf16(qa[s], bb, sa[t], 0, 0, 0);
            }
        }
        #pragma unroll
        for (int t = 0; t < 8; ++t) {
            #pragma unroll
            for (int r = 0; r < 4; ++r) {
                const int kg = c * 128 + t * 16 + lr;
                const int qg = qg0 + hi * 4 + r;
                sa[t][r] = (kg > qg) ? -1e30f : sa[t][r] * 0.125f;
            }
        }
        #pragma unroll
        for (int r = 0; r < 4; ++r) {
            float mx = -INFINITY;
            #pragma unroll
            for (int t = 0; t < 8; ++t) mx = fmaxf(mx, sa[t][r]);
            mx = fmaxf(mx, __shfl_xor(mx, 1));
            mx = fmaxf(mx, __shfl_xor(mx, 2));
            mx = fmaxf(mx, __shfl_xor(mx, 4));
            mx = fmaxf(mx, __shfl_xor(mx, 8));
            const float mn = fmaxf(m_run[r], mx);
            float sum = 0.f;
            #pragma unroll
            for (int t = 0; t < 8; ++t) {
                float p = __expf(sa[t][r] - mn);
                sa[t][r] = p;
                sum += p;
            }
            sum += __shfl_xor(sum, 1);
            sum += __shfl_xor(sum, 2);
            sum += __shfl_xor(sum, 4);
            sum += __shfl_xor(sum, 8);
            const float sc = __expf(m_run[r] - mn);
            l_run[r] = l_run[r] * sc + sum;
            m_run[r] = mn;
            #pragma unroll
            for (int t = 0; t < 4; ++t) accO[t][r] *= sc;
        }
        #pragma unroll
        for (int t = 0; t < 8; ++t)
            #pragma unroll
            for (int r = 0; r < 4; ++r)
                Pl[(hi * 4 + r) * 136 + t * 16 + lr] = f2bf(sa[t][r]);

        #pragma unroll
        for (int s = 0; s < 4; ++s) {
            const unsigned short* ap = Pl + lr * 136 + s * 32 + hi * 8;
            bf16x4 a0 = *(const bf16x4*)ap;
            bf16x4 a1 = *(const bf16x4*)(ap + 4);
            bf16x8 aa = __builtin_shufflevector(a0, a1, 0,1,2,3,4,5,6,7);
            #pragma unroll
            for (int t = 0; t < 4; ++t) {
                const unsigned short* bp = Vt + (t * 16 + lr) * 136 + s * 32 + hi * 8;
                bf16x4 b0 = *(const bf16x4*)bp;
                bf16x4 b1 = *(const bf16x4*)(bp + 4);
                bf16x8 bb = __builtin_shufflevector(b0, b1, 0,1,2,3,4,5,6,7);
                accO[t] = __builtin_amdgcn_mfma_f32_16x16x32_bf16(aa, bb, accO[t], 0, 0, 0);
            }
        }
    }

    float inv[4];
    #pragma unroll
    for (int r = 0; r < 4; ++r) inv[r] = 1.f / l_run[r];

    __syncthreads();
    float* Of = (float*)smem;   // [128][68] f32 = 34816 B, overlays smem
    #pragma unroll
    for (int t = 0; t < 4; ++t)
        #pragma unroll
        for (int r = 0; r < 4; ++r)
            Of[(w * 16 + hi * 4 + r) * 68 + t * 16 + lr] = accO[t][r] * inv[r];
    __syncthreads();
    #pragma unroll
    for (int i = 0; i < 2; ++i) {
        int e = tid + i * 512;
        int r = e >> 3, ch = e & 7;
        const float* src = Of + r * 68 + ch * 8;
        float4 v0 = *(const float4*)(src);
        float4 v1 = *(const float4*)(src + 4);
        bf16x8 o;
        o[0] = (short)f2bf(v0.x); o[1] = (short)f2bf(v0.y);
        o[2] = (short)f2bf(v0.z); o[3] = (short)f2bf(v0.w);
        o[4] = (short)f2bf(v1.x); o[5] = (short)f2bf(v1.y);
        o[6] = (short)f2bf(v1.z); o[7] = (short)f2bf(v1.w);
        *(bf16x8*)(ctxb + ((size_t)(b * SS + qt * 128 + r)) * DD + h * HD + ch * 8) = o;
    }
}

// ---------------------------------------------------------------------------
// xo = LayerNorm(x + P0+P1+P2+P3 + bias) * w + b ; P = bf16 partials.
// xo may equal x (in-place) or point at d_out for the final LN.
// ---------------------------------------------------------------------------
__global__ __launch_bounds__(256)
void ln_kernel(const float* __restrict__ x, float* __restrict__ xo,
               const unsigned short* __restrict__ P,
               const float* __restrict__ bias,
               const float* __restrict__ w, const float* __restrict__ b,
               unsigned short* __restrict__ xb)
{
    const size_t PS = (size_t)BSD;   // partial stride
    const int row = blockIdx.x;
    const int t   = threadIdx.x;
    const int d0  = t * 4;
    const float* xr = x + (size_t)row * DD;
    float* xor_ = xo + (size_t)row * DD;
    unsigned short* xbr = xb + (size_t)row * DD;
    const size_t base = (size_t)row * DD + d0;

    float4 xv = *(const float4*)(xr + d0);
    float4 bv = *(const float4*)(bias + d0);
    float z[4] = {xv.x + bv.x, xv.y + bv.y, xv.z + bv.z, xv.w + bv.w};
    #pragma unroll
    for (int p = 0; p < 4; ++p) {
        ushort4 pv = *(const ushort4*)(P + base + p * PS);
        z[0] += bf2f(pv.x); z[1] += bf2f(pv.y); z[2] += bf2f(pv.z); z[3] += bf2f(pv.w);
    }
    float s = z[0] + z[1] + z[2] + z[3];
    float ss = z[0]*z[0] + z[1]*z[1] + z[2]*z[2] + z[3]*z[3];

    #pragma unroll
    for (int off = 32; off; off >>= 1) {
        s  += __shfl_down(s, off);
        ss += __shfl_down(ss, off);
    }
    __shared__ float sbuf[4], ssbuf[4];
    const int wave = t >> 6, lane = t & 63;
    if (lane == 0) { sbuf[wave] = s; ssbuf[wave] = ss; }
    __syncthreads();
    if (t == 0) {
        float S = 0.f, SSum = 0.f;
        #pragma unroll
        for (int i = 0; i < 4; ++i) { S += sbuf[i]; SSum += ssbuf[i]; }
        float mean = S * (1.f / 1024.f);
        float var  = SSum * (1.f / 1024.f) - mean * mean;
        sbuf[0]  = mean;
        ssbuf[0] = rsqrtf(var + 1e-5f);
    }
    __syncthreads();
    const float mean = sbuf[0], rstd = ssbuf[0];

    float4 wv = *(const float4*)(w + d0);
    float4 bb = *(const float4*)(b + d0);
    float o0 = (z[0] - mean) * rstd * wv.x + bb.x;
    float o1 = (z[1] - mean) * rstd * wv.y + bb.y;
    float o2 = (z[2] - mean) * rstd * wv.z + bb.z;
    float o3 = (z[3] - mean) * rstd * wv.w + bb.w;
    *(float4*)(xor_ + d0) = make_float4(o0, o1, o2, o3);
    ushort4 ob4;
    ob4.x = f2bf(o0); ob4.y = f2bf(o1); ob4.z = f2bf(o2); ob4.w = f2bf(o3);
    *(ushort4*)(xbr + d0) = ob4;
}

// ---------------------------------------------------------------------------
extern "C" void kernel_launch(void* const* d_in, const int* in_sizes, int n_in,
                              void* d_out, int out_size, void* d_ws, size_t ws_size,
                              hipStream_t stream)
{
    const float* x_in  = (const float*)d_in[0];
    const float* qkv_w = (const float*)d_in[2];
    const float* qkv_b = (const float*)d_in[3];
    const float* out_w = (const float*)d_in[4];
    const float* out_b = (const float*)d_in[5];
    const float* w1    = (const float*)d_in[6];
    const float* b1    = (const float*)d_in[7];
    const float* w2    = (const float*)d_in[8];
    const float* b2    = (const float*)d_in[9];
    const float* ln1w  = (const float*)d_in[10];
    const float* ln1b  = (const float*)d_in[11];
    const float* ln2w  = (const float*)d_in[12];
    const float* ln2b  = (const float*)d_in[13];

    float* out_x = (float*)d_out;                    // [B,S,D]
    float* out_k = out_x + (size_t)BSD;              // [L,B,S,D]
    float* out_v = out_k + (size_t)LL * BSD;         // [L,B,S,D]

    const size_t MEG = 1024 * 1024;
    float* ws = (float*)d_ws;
    float*          xbuf  = ws;                               // 2M f32 (8 MB)
    unsigned short* part16= (unsigned short*)(ws + 2 * MEG);  // 4 x 2M bf16 (16 MB)
    unsigned short* xb16  = (unsigned short*)(ws + 6 * MEG);  // 2M bf16
    unsigned short* ctxb  = (unsigned short*)(ws + 7 * MEG);  // 2M bf16
    unsigned short* hb16  = (unsigned short*)(ws + 8 * MEG);  // 8M bf16 (16 MB)
    unsigned short* qb16  = hb16;                             // aliases (disjoint lifetime)
    unsigned short* kb16  = hb16 + 2 * MEG;
    unsigned short* vb16  = hb16 + 4 * MEG;
    unsigned short* wAll  = (unsigned short*)(ws + 12 * MEG); // 96M bf16 (192 MB)

    unsigned short* qkvW = wAll;                     // 24M
    unsigned short* outW = wAll + 24 * MEG;          //  8M
    unsigned short* w1W  = wAll + 32 * MEG;          // 32M
    unsigned short* w2W  = wAll + 64 * MEG;          // 32M

    cvt_bf16<<<24 * MEG / 1024, 256, 0, stream>>>(qkv_w, qkvW);
    cvt_bf16<<< 8 * MEG / 1024, 256, 0, stream>>>(out_w, outW);
    cvt_bf16<<<32 * MEG / 1024, 256, 0, stream>>>(w1,    w1W);
    cvt_bf16<<<32 * MEG / 1024, 256, 0, stream>>>(w2,    w2W);
    cvt_x<<<BSD / 1024, 256, 0, stream>>>(x_in, xbuf, xb16);

    const int M = BB * SS;   // 2048

    for (int l = 0; l < LL; ++l) {
        const float* qb  = qkv_b + (size_t)l * 3 * DD;
        const float* ob  = out_b + (size_t)l * DD;
        const float* b1l = b1    + (size_t)l * FFD;
        const float* b2l = b2    + (size_t)l * DD;
        const unsigned short* qwl = qkvW + (size_t)l * 3 * DD * DD;
        const unsigned short* owl = outW + (size_t)l * DD * DD;
        const unsigned short* w1l = w1W  + (size_t)l * FFD * DD;
        const unsigned short* w2l = w2W  + (size_t)l * DD * FFD;
        float* kc = out_k + (size_t)l * BSD;
        float* vc = out_v + (size_t)l * BSD;

        // 1. QKV projection (full K): q/k/v bf16 + f32 caches
        gemm_bf16<<<dim3(3 * DD / 128, M / 128, 1), 512, 0, stream>>>(
            xb16, qwl, qb, nullptr, qb16, kc, vc, kb16, vb16, M, 3 * DD, DD, 2);

        // 2. MFMA causal attention -> bf16 ctx
        attn_mfma<<<dim3(SS / 128, HH, BB), 512, 0, stream>>>(qb16, kb16, vb16, ctxb);

        // 3. output projection, split-K x4 -> bf16 partials
        gemm_bf16<<<dim3(DD / 128, M / 128, 4), 512, 0, stream>>>(
            ctxb, owl, nullptr, nullptr, part16, nullptr, nullptr, nullptr, nullptr,
            M, DD, DD / 4, 3);

        // 4. x = LN(x + Σpart + ob)
        ln_kernel<<<M, 256, 0, stream>>>(xbuf, xbuf, part16, ob,
                                         ln1w + (size_t)l * DD, ln1b + (size_t)l * DD, xb16);

        // 5. h = relu(x @ w1^T + b1) -> bf16
        gemm_bf16<<<dim3(FFD / 128, M / 128, 1), 512, 0, stream>>>(
            xb16, w1l, b1l, nullptr, hb16, nullptr, nullptr, nullptr, nullptr,
            M, FFD, DD, 1);

        // 6. mlp = h @ w2^T, split-K x4 -> bf16 partials
        gemm_bf16<<<dim3(DD / 128, M / 128, 4), 512, 0, stream>>>(
            hb16, w2l, nullptr, nullptr, part16, nullptr, nullptr, nullptr, nullptr,
            M, DD, FFD / 4, 3);

        // 7. x = LN(x + Σpart + b2); last layer writes d_out directly
        float* xo = (l == LL - 1) ? out_x : xbuf;
        ln_kernel<<<M, 256, 0, stream>>>(xbuf, xo, part16, b2l,
                                         ln2w + (size_t)l * DD, ln2b + (size_t)l * DD, xb16);
    }
}